// Round 1
// baseline (350.685 us; speedup 1.0000x reference)
//
#include <hip/hip_runtime.h>

// CausalSelfAttention: B=2 S=2048 H=16 D=64 HID=1024, fp32 in/out, bf16 MFMA compute.
//
// Pipeline: cvt(x,W*) -> bf16 | QKV GEMMs (x@W.T+b) -> Q,K [b,h,s,d], V^T [b,h,d,s]
//           | flash attn (swapped QK^T, online softmax, barrier-free) -> Y [b,s,hid]
//           | out GEMM (Y@Wp.T+bp) -> fp32 d_out.
//
// MFMA layout discipline: operand k-slot bijection is CHOSEN as sigma(g,j)=g*8+j
// (g=lane>>4, j=0..7) and used consistently for BOTH A and B operands of every
// MFMA -> result invariant to the true HW bijection. P goes through an
// explicitly-addressed LDS tile before re-entering as an operand.
// C/D layout (verified): col = lane&15, row = (lane>>4)*4 + reg.

typedef unsigned short u16;
typedef float f32x4 __attribute__((ext_vector_type(4)));
typedef __bf16 bf16x8 __attribute__((ext_vector_type(8)));
typedef unsigned int u32x4 __attribute__((ext_vector_type(4)));
typedef unsigned short u16x4 __attribute__((ext_vector_type(4)));

constexpr int Bn = 2, SEQ = 2048, NH = 16, HD = 64, HID = 1024;

__device__ __forceinline__ u16 f2bf(float f) {
  unsigned u = __float_as_uint(f);
  u += 0x7fff + ((u >> 16) & 1);  // RNE
  return (u16)(u >> 16);
}

__device__ __forceinline__ f32x4 mfma16(bf16x8 a, bf16x8 b, f32x4 c) {
  return __builtin_amdgcn_mfma_f32_16x16x32_bf16(a, b, c, 0, 0, 0);
}

__global__ void cvt_kernel(const float* __restrict__ in, u16* __restrict__ out, int n) {
  int i = (blockIdx.x * blockDim.x + threadIdx.x) * 4;
  if (i + 3 < n) {
    float4 v = *reinterpret_cast<const float4*>(in + i);
    u16x4 o = {f2bf(v.x), f2bf(v.y), f2bf(v.z), f2bf(v.w)};
    *reinterpret_cast<u16x4*>(out + i) = o;
  }
}

// C = A[M,K] * B[N,K]^T + bias[N].  mode 0: bf16 out at [b,h,s,d];
// mode 1: bf16 out at [b,h,d,s] (V^T); mode 2: fp32 out row-major [M,N].
__global__ __launch_bounds__(256) void gemm_bt(
    const u16* __restrict__ A, const u16* __restrict__ Bm,
    const float* __restrict__ bias, void* __restrict__ outp,
    int M, int N, int K, int mode)
{
  __shared__ u16 As[128 * 32];
  __shared__ u16 Bs[128 * 32];
  const int tid = threadIdx.x;
  const int lane = tid & 63, w = tid >> 6;
  const int wr = w >> 1, wc = w & 1;
  const int l15 = lane & 15, g = lane >> 4;
  const int m0 = blockIdx.x * 128, n0 = blockIdx.y * 128;

  f32x4 acc[4][4] = {};

  for (int kt = 0; kt < K; kt += 32) {
    __syncthreads();
#pragma unroll
    for (int i = 0; i < 2; i++) {
      int chunk = tid + 256 * i;
      int r = chunk >> 2, c = (chunk & 3) << 3;
      *reinterpret_cast<u32x4*>(&As[r * 32 + c]) =
          *reinterpret_cast<const u32x4*>(&A[(size_t)(m0 + r) * K + kt + c]);
      *reinterpret_cast<u32x4*>(&Bs[r * 32 + c]) =
          *reinterpret_cast<const u32x4*>(&Bm[(size_t)(n0 + r) * K + kt + c]);
    }
    __syncthreads();
    bf16x8 af[4], bfr[4];
#pragma unroll
    for (int mi = 0; mi < 4; mi++)
      af[mi] = *reinterpret_cast<const bf16x8*>(&As[(wr * 64 + mi * 16 + l15) * 32 + g * 8]);
#pragma unroll
    for (int ni = 0; ni < 4; ni++)
      bfr[ni] = *reinterpret_cast<const bf16x8*>(&Bs[(wc * 64 + ni * 16 + l15) * 32 + g * 8]);
#pragma unroll
    for (int mi = 0; mi < 4; mi++)
#pragma unroll
      for (int ni = 0; ni < 4; ni++)
        acc[mi][ni] = mfma16(af[mi], bfr[ni], acc[mi][ni]);
  }

  float bv[4];
#pragma unroll
  for (int ni = 0; ni < 4; ni++) bv[ni] = bias[n0 + wc * 64 + ni * 16 + l15];

  if (mode == 2) {
    float* out = (float*)outp;
#pragma unroll
    for (int mi = 0; mi < 4; mi++)
#pragma unroll
      for (int ni = 0; ni < 4; ni++)
#pragma unroll
        for (int r = 0; r < 4; r++) {
          int gm = m0 + wr * 64 + mi * 16 + g * 4 + r;
          int gn = n0 + wc * 64 + ni * 16 + l15;
          out[(size_t)gm * N + gn] = acc[mi][ni][r] + bv[ni];
        }
  } else {
    u16* out = (u16*)outp;
#pragma unroll
    for (int mi = 0; mi < 4; mi++)
#pragma unroll
      for (int ni = 0; ni < 4; ni++)
#pragma unroll
        for (int r = 0; r < 4; r++) {
          int gm = m0 + wr * 64 + mi * 16 + g * 4 + r;
          int gn = n0 + wc * 64 + ni * 16 + l15;
          int bb = gm >> 11, sq = gm & (SEQ - 1);
          int hh = gn >> 6, d = gn & 63;
          size_t off = (mode == 0)
              ? (((size_t)(bb * NH + hh) * SEQ + sq) * HD + d)
              : (((size_t)(bb * NH + hh) * HD + d) * SEQ + sq);
          out[off] = f2bf(acc[mi][ni][r] + bv[ni]);
        }
  }
}

// Flash attention, causal. Grid (S/64, H, B), 4 waves/block; wave w owns q rows
// [q0, q0+16). Swapped QK^T: S^T[key][q] so q = lane&15 -> per-lane softmax state.
// Barrier-free: P_lds is per-wave, loop bound per-wave.
__global__ __launch_bounds__(256) void attn_kernel(
    const u16* __restrict__ Q, const u16* __restrict__ Kt,
    const u16* __restrict__ Vt, u16* __restrict__ Y)
{
  __shared__ u16 Plds[4][16][32];  // [wave][q][key]
  const int tid = threadIdx.x;
  const int lane = tid & 63, w = tid >> 6;
  const int l15 = lane & 15, g = lane >> 4;
  const int h = blockIdx.y, b = blockIdx.z;
  const int q0 = blockIdx.x * 64 + w * 16;
  const int qg = q0 + l15;

  const size_t bh = (size_t)(b * NH + h);
  const u16* Qp = Q + bh * SEQ * HD;
  const u16* Kp = Kt + bh * SEQ * HD;
  const u16* Vp = Vt + bh * HD * SEQ;  // [d][s]

  // Q fragments (B operand: n=q=lane&15), scale 1/8 folded in (exact pow2 in bf16)
  bf16x8 qf[2];
#pragma unroll
  for (int hf = 0; hf < 2; hf++) {
    bf16x8 t = *reinterpret_cast<const bf16x8*>(Qp + (size_t)qg * HD + hf * 32 + g * 8);
#pragma unroll
    for (int j = 0; j < 8; j++) qf[hf][j] = (__bf16)((float)t[j] * 0.125f);
  }

  float m_run = -__builtin_inff(), l_run = 0.0f;
  f32x4 o[4] = {};  // O^T[d][q]: d = db*16 + g*4 + r, q = l15

  for (int kt = 0; kt <= q0 + 15; kt += 32) {
    // S^T[key][q] for 32 keys: two 16-key MFMAs x two d-halves
    f32x4 sa[2];
#pragma unroll
    for (int sub = 0; sub < 2; sub++) {
      f32x4 a = {0.f, 0.f, 0.f, 0.f};
#pragma unroll
      for (int hf = 0; hf < 2; hf++) {
        bf16x8 kf = *reinterpret_cast<const bf16x8*>(
            Kp + (size_t)(kt + sub * 16 + l15) * HD + hf * 32 + g * 8);
        a = mfma16(kf, qf[hf], a);
      }
      sa[sub] = a;
    }

    // causal mask + online softmax (per q column = per lane, keys spread over
    // 8 regs x 4 lane-groups; reduce in-lane then shfl_xor 16,32)
    float p[8];
    float tmax = -__builtin_inff();
#pragma unroll
    for (int sub = 0; sub < 2; sub++)
#pragma unroll
      for (int r = 0; r < 4; r++) {
        int key = kt + sub * 16 + g * 4 + r;
        float sv = (key <= qg) ? sa[sub][r] : -__builtin_inff();
        p[sub * 4 + r] = sv;
        tmax = fmaxf(tmax, sv);
      }
    tmax = fmaxf(tmax, __shfl_xor(tmax, 16));
    tmax = fmaxf(tmax, __shfl_xor(tmax, 32));

    float mnew = fmaxf(m_run, tmax);
    float fscale = __expf(m_run - mnew);
    float psum = 0.f;
    u16x4 pw0, pw1;
#pragma unroll
    for (int i = 0; i < 8; i++) {
      float pv = __expf(p[i] - mnew);
      psum += pv;
      if (i < 4) pw0[i] = f2bf(pv);
      else       pw1[i - 4] = f2bf(pv);
    }
    psum += __shfl_xor(psum, 16);
    psum += __shfl_xor(psum, 32);
    l_run = l_run * fscale + psum;
    m_run = mnew;
#pragma unroll
    for (int db = 0; db < 4; db++) o[db] *= fscale;

    // P^T -> LDS [q][key] (explicit addressing: bijection-safe re-entry)
    *reinterpret_cast<u16x4*>(&Plds[w][l15][g * 4]) = pw0;
    *reinterpret_cast<u16x4*>(&Plds[w][l15][16 + g * 4]) = pw1;
    asm volatile("s_waitcnt lgkmcnt(0)" ::: "memory");  // wave-local LDS visibility
    bf16x8 pb = *reinterpret_cast<const bf16x8*>(&Plds[w][l15][g * 8]);

    // O^T += V^T * P^T : A = V^T (m=d), B = P^T (n=q), K=32 keys
#pragma unroll
    for (int db = 0; db < 4; db++) {
      bf16x8 va = *reinterpret_cast<const bf16x8*>(
          Vp + (size_t)(db * 16 + l15) * SEQ + kt + g * 8);
      o[db] = mfma16(va, pb, o[db]);
    }
  }

  float rl = 1.0f / l_run;
#pragma unroll
  for (int db = 0; db < 4; db++) {
    u16x4 yo;
#pragma unroll
    for (int r = 0; r < 4; r++) yo[r] = f2bf(o[db][r] * rl);
    *reinterpret_cast<u16x4*>(
        Y + ((size_t)(b * SEQ) + qg) * HID + h * HD + db * 16 + g * 4) = yo;
  }
}

extern "C" void kernel_launch(void* const* d_in, const int* in_sizes, int n_in,
                              void* d_out, int out_size, void* d_ws, size_t ws_size,
                              hipStream_t stream) {
  const float* x  = (const float*)d_in[0];
  const float* Wq = (const float*)d_in[1];
  const float* bq = (const float*)d_in[2];
  const float* Wk = (const float*)d_in[3];
  const float* bk = (const float*)d_in[4];
  const float* Wv = (const float*)d_in[5];
  const float* bv = (const float*)d_in[6];
  const float* Wp = (const float*)d_in[7];
  const float* bp = (const float*)d_in[8];

  u16* ws = (u16*)d_ws;
  const size_t NX = (size_t)Bn * SEQ * HID;  // 4,194,304
  const size_t NW = (size_t)HID * HID;       // 1,048,576
  u16* xb  = ws; ws += NX;
  u16* wqb = ws; ws += NW;
  u16* wkb = ws; ws += NW;
  u16* wvb = ws; ws += NW;
  u16* wpb = ws; ws += NW;
  u16* Qb  = ws; ws += NX;
  u16* Kb  = ws; ws += NX;
  u16* Vtb = ws; ws += NX;
  u16* Yb  = ws; ws += NX;   // total ~48 MB of d_ws

  cvt_kernel<<<dim3((unsigned)(NX / 1024)), 256, 0, stream>>>(x, xb, (int)NX);
  cvt_kernel<<<dim3((unsigned)(NW / 1024)), 256, 0, stream>>>(Wq, wqb, (int)NW);
  cvt_kernel<<<dim3((unsigned)(NW / 1024)), 256, 0, stream>>>(Wk, wkb, (int)NW);
  cvt_kernel<<<dim3((unsigned)(NW / 1024)), 256, 0, stream>>>(Wv, wvb, (int)NW);
  cvt_kernel<<<dim3((unsigned)(NW / 1024)), 256, 0, stream>>>(Wp, wpb, (int)NW);

  dim3 gg(4096 / 128, 1024 / 128);
  gemm_bt<<<gg, 256, 0, stream>>>(xb, wqb, bq, Qb,  4096, 1024, 1024, 0);
  gemm_bt<<<gg, 256, 0, stream>>>(xb, wkb, bk, Kb,  4096, 1024, 1024, 0);
  gemm_bt<<<gg, 256, 0, stream>>>(xb, wvb, bv, Vtb, 4096, 1024, 1024, 1);

  attn_kernel<<<dim3(SEQ / 64, NH, Bn), 256, 0, stream>>>(Qb, Kb, Vtb, Yb);

  gemm_bt<<<gg, 256, 0, stream>>>(Yb, wpb, bp, d_out, 4096, 1024, 1024, 2);
}

// Round 2
// 307.369 us; speedup vs baseline: 1.1409x; 1.1409x over previous
//
#include <hip/hip_runtime.h>

// CausalSelfAttention: B=2 S=2048 H=16 D=64 HID=1024, fp32 in/out, bf16 MFMA compute.
//
// R2 changes vs R1:
//  - attn: P never leaves registers (chosen k-slot bijection sigma2 shared by P and V
//    fragments), 64 keys/iter, exp2-domain softmax, defer-max (THR=11 log2), balanced
//    tile->wave mapping {j, 63-j, 64+j, 127-j}. Zero LDS, barrier-free.
//  - gemm: staging via global_load_lds width=16 (async HBM->LDS, no VGPR roundtrip).
//
// MFMA layout discipline: each MFMA's operand k-slot bijection is CHOSEN and used
// consistently for BOTH its A and B operands -> result invariant to the true HW
// bijection. QK uses sigma1(g,j)=g*8+j (contiguous 16B loads); PV uses
// sigma2(g,j)=(j>>2)*16+g*4+(j&3) (matches QK^T C/D register layout, so P stays
// in-register). C/D layout (verified): col = lane&15, row = (lane>>4)*4 + reg.

typedef unsigned short u16;
typedef float f32x4 __attribute__((ext_vector_type(4)));
typedef __bf16 bf16x8 __attribute__((ext_vector_type(8)));
typedef unsigned int u32x4 __attribute__((ext_vector_type(4)));
typedef unsigned short u16x4 __attribute__((ext_vector_type(4)));
typedef unsigned short u16x8 __attribute__((ext_vector_type(8)));

constexpr int Bn = 2, SEQ = 2048, NH = 16, HD = 64, HID = 1024;

__device__ __forceinline__ u16 f2bf(float f) {
  unsigned u = __float_as_uint(f);
  u += 0x7fff + ((u >> 16) & 1);  // RNE
  return (u16)(u >> 16);
}

__device__ __forceinline__ f32x4 mfma16(bf16x8 a, bf16x8 b, f32x4 c) {
  return __builtin_amdgcn_mfma_f32_16x16x32_bf16(a, b, c, 0, 0, 0);
}

__device__ __forceinline__ void gload16(const u16* g, u16* l) {
  __builtin_amdgcn_global_load_lds(
      (const __attribute__((address_space(1))) unsigned int*)(const void*)g,
      (__attribute__((address_space(3))) unsigned int*)(void*)l, 16, 0, 0);
}

__global__ void cvt_kernel(const float* __restrict__ in, u16* __restrict__ out, int n) {
  int i = (blockIdx.x * blockDim.x + threadIdx.x) * 4;
  if (i + 3 < n) {
    float4 v = *reinterpret_cast<const float4*>(in + i);
    u16x4 o = {f2bf(v.x), f2bf(v.y), f2bf(v.z), f2bf(v.w)};
    *reinterpret_cast<u16x4*>(out + i) = o;
  }
}

// C = A[M,K] * B[N,K]^T + bias[N].  mode 0: bf16 out at [b,h,s,d];
// mode 1: bf16 out at [b,h,d,s] (V^T); mode 2: fp32 out row-major [M,N].
__global__ __launch_bounds__(256) void gemm_bt(
    const u16* __restrict__ A, const u16* __restrict__ Bm,
    const float* __restrict__ bias, void* __restrict__ outp,
    int M, int N, int K, int mode)
{
  __shared__ u16 As[128 * 32];
  __shared__ u16 Bs[128 * 32];
  const int tid = threadIdx.x;
  const int lane = tid & 63, w = tid >> 6;
  const int wr = w >> 1, wc = w & 1;
  const int l15 = lane & 15, g = lane >> 4;
  const int m0 = blockIdx.x * 128, n0 = blockIdx.y * 128;

  f32x4 acc[4][4] = {};

  for (int kt = 0; kt < K; kt += 32) {
    __syncthreads();
#pragma unroll
    for (int i = 0; i < 2; i++) {
      int chunk = tid + 256 * i;
      int r = chunk >> 2, c = (chunk & 3) << 3;
      gload16(&A[(size_t)(m0 + r) * K + kt + c], &As[(size_t)chunk * 8]);
      gload16(&Bm[(size_t)(n0 + r) * K + kt + c], &Bs[(size_t)chunk * 8]);
    }
    __syncthreads();
    bf16x8 af[4], bfr[4];
#pragma unroll
    for (int mi = 0; mi < 4; mi++)
      af[mi] = *reinterpret_cast<const bf16x8*>(&As[(wr * 64 + mi * 16 + l15) * 32 + g * 8]);
#pragma unroll
    for (int ni = 0; ni < 4; ni++)
      bfr[ni] = *reinterpret_cast<const bf16x8*>(&Bs[(wc * 64 + ni * 16 + l15) * 32 + g * 8]);
#pragma unroll
    for (int mi = 0; mi < 4; mi++)
#pragma unroll
      for (int ni = 0; ni < 4; ni++)
        acc[mi][ni] = mfma16(af[mi], bfr[ni], acc[mi][ni]);
  }

  float bv[4];
#pragma unroll
  for (int ni = 0; ni < 4; ni++) bv[ni] = bias[n0 + wc * 64 + ni * 16 + l15];

  if (mode == 2) {
    float* out = (float*)outp;
#pragma unroll
    for (int mi = 0; mi < 4; mi++)
#pragma unroll
      for (int ni = 0; ni < 4; ni++)
#pragma unroll
        for (int r = 0; r < 4; r++) {
          int gm = m0 + wr * 64 + mi * 16 + g * 4 + r;
          int gn = n0 + wc * 64 + ni * 16 + l15;
          out[(size_t)gm * N + gn] = acc[mi][ni][r] + bv[ni];
        }
  } else {
    u16* out = (u16*)outp;
#pragma unroll
    for (int mi = 0; mi < 4; mi++)
#pragma unroll
      for (int ni = 0; ni < 4; ni++)
#pragma unroll
        for (int r = 0; r < 4; r++) {
          int gm = m0 + wr * 64 + mi * 16 + g * 4 + r;
          int gn = n0 + wc * 64 + ni * 16 + l15;
          int bb = gm >> 11, sq = gm & (SEQ - 1);
          int hh = gn >> 6, d = gn & 63;
          size_t off = (mode == 0)
              ? (((size_t)(bb * NH + hh) * SEQ + sq) * HD + d)
              : (((size_t)(bb * NH + hh) * HD + d) * SEQ + sq);
          out[off] = f2bf(acc[mi][ni][r] + bv[ni]);
        }
  }
}

// Flash attention, causal, zero-LDS. Grid (32, H, B), 4 waves/block.
// Wave w of block j owns 16-q-row tile t in {j, 63-j, 64+j, 127-j} (work-balanced).
// Swapped QK^T -> per-lane softmax state (q = lane&15); P stays in registers
// (sigma2 bijection); softmax in exp2 domain with defer-max.
__global__ __launch_bounds__(256, 4) void attn_kernel(
    const u16* __restrict__ Q, const u16* __restrict__ Kt,
    const u16* __restrict__ Vt, u16* __restrict__ Y)
{
  const int tid = threadIdx.x;
  const int lane = tid & 63, w = tid >> 6;
  const int l15 = lane & 15, g = lane >> 4;
  const int h = blockIdx.y, b = blockIdx.z;
  const int j = blockIdx.x;
  int t;
  if (w == 0) t = j;
  else if (w == 1) t = 63 - j;
  else if (w == 2) t = 64 + j;
  else t = 127 - j;
  const int q0 = t * 16;
  const int qg = q0 + l15;

  const size_t bh = (size_t)(b * NH + h);
  const u16* Qp = Q + bh * SEQ * HD;
  const u16* Kp = Kt + bh * SEQ * HD;
  const u16* Vp = Vt + bh * HD * SEQ;  // [d][s]

  // Q fragments (B operand, sigma1), scale (1/8)*log2(e) folded in -> exp2 domain
  const float QSC = 0.125f * 1.44269504088896f;
  bf16x8 qf[2];
#pragma unroll
  for (int hf = 0; hf < 2; hf++) {
    bf16x8 tq = *reinterpret_cast<const bf16x8*>(Qp + (size_t)qg * HD + hf * 32 + g * 8);
#pragma unroll
    for (int jj = 0; jj < 8; jj++) qf[hf][jj] = (__bf16)((float)tq[jj] * QSC);
  }

  const float NEG = -__builtin_inff();
  float m_run = NEG, l_run = 0.0f;
  f32x4 o[4] = {};  // O^T[d][q]: d = db*16 + g*4 + r, q = l15

  for (int kt = 0; kt <= q0 + 15; kt += 64) {
    // S^T (log2-domain) for 64 keys: key = kt + sub*16 + g*4 + r, q = l15
    f32x4 sa[4];
#pragma unroll
    for (int sub = 0; sub < 4; sub++) {
      f32x4 a = {0.f, 0.f, 0.f, 0.f};
#pragma unroll
      for (int hf = 0; hf < 2; hf++) {
        bf16x8 kf = *reinterpret_cast<const bf16x8*>(
            Kp + (size_t)(kt + sub * 16 + l15) * HD + hf * 32 + g * 8);
        a = mfma16(kf, qf[hf], a);
      }
      sa[sub] = a;
    }

    // causal mask; per-q (per-lane-column) max via tree + shfl
    float p[16];
#pragma unroll
    for (int sub = 0; sub < 4; sub++)
#pragma unroll
      for (int r = 0; r < 4; r++) {
        int key = kt + sub * 16 + g * 4 + r;
        p[sub * 4 + r] = (key <= qg) ? sa[sub][r] : NEG;
      }
    float t8[8], t4[4], t2[2];
#pragma unroll
    for (int i = 0; i < 8; i++) t8[i] = fmaxf(p[i], p[i + 8]);
#pragma unroll
    for (int i = 0; i < 4; i++) t4[i] = fmaxf(t8[i], t8[i + 4]);
    t2[0] = fmaxf(t4[0], t4[2]); t2[1] = fmaxf(t4[1], t4[3]);
    float tmax = fmaxf(t2[0], t2[1]);
    tmax = fmaxf(tmax, __shfl_xor(tmax, 16));
    tmax = fmaxf(tmax, __shfl_xor(tmax, 32));

    // defer-max: only rescale when max grew by > 11 (log2 units, ~ e^7.6)
    if (__any(tmax > m_run + 11.0f)) {
      float mnew = fmaxf(m_run, tmax);
      float fs = __builtin_amdgcn_exp2f(m_run - mnew);  // 0 when m_run=-inf
      l_run *= fs;
#pragma unroll
      for (int db = 0; db < 4; db++) o[db] *= fs;
      m_run = mnew;
    }

    // P = 2^(p - m_run), sum-tree, pack to bf16
    float s4[4] = {0.f, 0.f, 0.f, 0.f};
    u16x4 pw[4];
#pragma unroll
    for (int i = 0; i < 16; i++) {
      float pv = __builtin_amdgcn_exp2f(p[i] - m_run);
      s4[i & 3] += pv;
      pw[i >> 2][i & 3] = f2bf(pv);
    }
    float psum = (s4[0] + s4[1]) + (s4[2] + s4[3]);
    psum += __shfl_xor(psum, 16);
    psum += __shfl_xor(psum, 32);
    l_run += psum;

    // O^T += V^T * P^T, two 32-key halves; sigma2(g,j) = (j>>2)*16 + g*4 + (j&3)
#pragma unroll
    for (int half = 0; half < 2; half++) {
      u16x8 pbu;
#pragma unroll
      for (int jj = 0; jj < 4; jj++) {
        pbu[jj] = pw[2 * half][jj];
        pbu[jj + 4] = pw[2 * half + 1][jj];
      }
      bf16x8 pb = __builtin_bit_cast(bf16x8, pbu);
#pragma unroll
      for (int db = 0; db < 4; db++) {
        const u16* vrow = Vp + (size_t)(db * 16 + l15) * SEQ + kt + 32 * half + g * 4;
        u16x4 v0 = *reinterpret_cast<const u16x4*>(vrow);
        u16x4 v1 = *reinterpret_cast<const u16x4*>(vrow + 16);
        u16x8 vau;
#pragma unroll
        for (int jj = 0; jj < 4; jj++) { vau[jj] = v0[jj]; vau[jj + 4] = v1[jj]; }
        bf16x8 va = __builtin_bit_cast(bf16x8, vau);
        o[db] = mfma16(va, pb, o[db]);
      }
    }
  }

  float rl = 1.0f / l_run;
#pragma unroll
  for (int db = 0; db < 4; db++) {
    u16x4 yo;
#pragma unroll
    for (int r = 0; r < 4; r++) yo[r] = f2bf(o[db][r] * rl);
    *reinterpret_cast<u16x4*>(
        Y + ((size_t)(b * SEQ) + qg) * HID + h * HD + db * 16 + g * 4) = yo;
  }
}

extern "C" void kernel_launch(void* const* d_in, const int* in_sizes, int n_in,
                              void* d_out, int out_size, void* d_ws, size_t ws_size,
                              hipStream_t stream) {
  const float* x  = (const float*)d_in[0];
  const float* Wq = (const float*)d_in[1];
  const float* bq = (const float*)d_in[2];
  const float* Wk = (const float*)d_in[3];
  const float* bk = (const float*)d_in[4];
  const float* Wv = (const float*)d_in[5];
  const float* bv = (const float*)d_in[6];
  const float* Wp = (const float*)d_in[7];
  const float* bp = (const float*)d_in[8];

  u16* ws = (u16*)d_ws;
  const size_t NX = (size_t)Bn * SEQ * HID;  // 4,194,304
  const size_t NW = (size_t)HID * HID;       // 1,048,576
  u16* xb  = ws; ws += NX;
  u16* wqb = ws; ws += NW;
  u16* wkb = ws; ws += NW;
  u16* wvb = ws; ws += NW;
  u16* wpb = ws; ws += NW;
  u16* Qb  = ws; ws += NX;
  u16* Kb  = ws; ws += NX;
  u16* Vtb = ws; ws += NX;
  u16* Yb  = ws; ws += NX;   // total ~48 MB of d_ws

  cvt_kernel<<<dim3((unsigned)(NX / 1024)), 256, 0, stream>>>(x, xb, (int)NX);
  cvt_kernel<<<dim3((unsigned)(NW / 1024)), 256, 0, stream>>>(Wq, wqb, (int)NW);
  cvt_kernel<<<dim3((unsigned)(NW / 1024)), 256, 0, stream>>>(Wk, wkb, (int)NW);
  cvt_kernel<<<dim3((unsigned)(NW / 1024)), 256, 0, stream>>>(Wv, wvb, (int)NW);
  cvt_kernel<<<dim3((unsigned)(NW / 1024)), 256, 0, stream>>>(Wp, wpb, (int)NW);

  dim3 gg(4096 / 128, 1024 / 128);
  gemm_bt<<<gg, 256, 0, stream>>>(xb, wqb, bq, Qb,  4096, 1024, 1024, 0);
  gemm_bt<<<gg, 256, 0, stream>>>(xb, wkb, bk, Kb,  4096, 1024, 1024, 0);
  gemm_bt<<<gg, 256, 0, stream>>>(xb, wvb, bv, Vtb, 4096, 1024, 1024, 1);

  attn_kernel<<<dim3(32, NH, Bn), 256, 0, stream>>>(Qb, Kb, Vtb, Yb);

  gemm_bt<<<gg, 256, 0, stream>>>(Yb, wpb, bp, d_out, 4096, 1024, 1024, 2);
}

// Round 3
// 200.101 us; speedup vs baseline: 1.7525x; 1.5361x over previous
//
#include <hip/hip_runtime.h>

// CausalSelfAttention: B=2 S=2048 H=16 D=64 HID=1024, fp32 in/out, bf16 MFMA compute.
//
// R3 changes vs R2 (attn only):
//  - Block-cooperative K/V staging: 4 waves share 64-key K [64x64] and V^T [64x64]
//    LDS tiles (8KB each), double-buffered, staged with global_load_lds width=16,
//    prefetched one iteration ahead, ONE __syncthreads per iteration.
//  - XOR swizzle (slot ^= row&7) via pre-swizzled GLOBAL source + swizzled LDS reads
//    (T2/m173 pattern; LDS itself stays linear for global_load_lds).
//  - P still never leaves registers (sigma2 bijection); softmax in exp2 domain with
//    defer-max (THR=11 log2) as in R2.
//
// MFMA layout discipline: each MFMA's operand k-slot bijection is CHOSEN and used
// consistently for BOTH its A and B operands -> result invariant to the true HW
// bijection. QK uses sigma1(g,j)=g*8+j; PV uses sigma2(g,j)=(j>>2)*16+g*4+(j&3)
// (matches QK^T C/D register layout). C/D: col = lane&15, row = (lane>>4)*4 + reg.

typedef unsigned short u16;
typedef float f32x4 __attribute__((ext_vector_type(4)));
typedef __bf16 bf16x8 __attribute__((ext_vector_type(8)));
typedef unsigned int u32x4 __attribute__((ext_vector_type(4)));
typedef unsigned short u16x4 __attribute__((ext_vector_type(4)));
typedef unsigned short u16x8 __attribute__((ext_vector_type(8)));

constexpr int Bn = 2, SEQ = 2048, NH = 16, HD = 64, HID = 1024;

__device__ __forceinline__ u16 f2bf(float f) {
  unsigned u = __float_as_uint(f);
  u += 0x7fff + ((u >> 16) & 1);  // RNE
  return (u16)(u >> 16);
}

__device__ __forceinline__ f32x4 mfma16(bf16x8 a, bf16x8 b, f32x4 c) {
  return __builtin_amdgcn_mfma_f32_16x16x32_bf16(a, b, c, 0, 0, 0);
}

__device__ __forceinline__ void gload16(const u16* g, u16* l) {
  __builtin_amdgcn_global_load_lds(
      (const __attribute__((address_space(1))) unsigned int*)(const void*)g,
      (__attribute__((address_space(3))) unsigned int*)(void*)l, 16, 0, 0);
}

__global__ void cvt_kernel(const float* __restrict__ in, u16* __restrict__ out, int n) {
  int i = (blockIdx.x * blockDim.x + threadIdx.x) * 4;
  if (i + 3 < n) {
    float4 v = *reinterpret_cast<const float4*>(in + i);
    u16x4 o = {f2bf(v.x), f2bf(v.y), f2bf(v.z), f2bf(v.w)};
    *reinterpret_cast<u16x4*>(out + i) = o;
  }
}

// C = A[M,K] * B[N,K]^T + bias[N].  mode 0: bf16 out at [b,h,s,d];
// mode 1: bf16 out at [b,h,d,s] (V^T); mode 2: fp32 out row-major [M,N].
__global__ __launch_bounds__(256) void gemm_bt(
    const u16* __restrict__ A, const u16* __restrict__ Bm,
    const float* __restrict__ bias, void* __restrict__ outp,
    int M, int N, int K, int mode)
{
  __shared__ u16 As[128 * 32];
  __shared__ u16 Bs[128 * 32];
  const int tid = threadIdx.x;
  const int lane = tid & 63, w = tid >> 6;
  const int wr = w >> 1, wc = w & 1;
  const int l15 = lane & 15, g = lane >> 4;
  const int m0 = blockIdx.x * 128, n0 = blockIdx.y * 128;

  f32x4 acc[4][4] = {};

  for (int kt = 0; kt < K; kt += 32) {
    __syncthreads();
#pragma unroll
    for (int i = 0; i < 2; i++) {
      int chunk = tid + 256 * i;
      int r = chunk >> 2, c = (chunk & 3) << 3;
      gload16(&A[(size_t)(m0 + r) * K + kt + c], &As[(size_t)chunk * 8]);
      gload16(&Bm[(size_t)(n0 + r) * K + kt + c], &Bs[(size_t)chunk * 8]);
    }
    __syncthreads();
    bf16x8 af[4], bfr[4];
#pragma unroll
    for (int mi = 0; mi < 4; mi++)
      af[mi] = *reinterpret_cast<const bf16x8*>(&As[(wr * 64 + mi * 16 + l15) * 32 + g * 8]);
#pragma unroll
    for (int ni = 0; ni < 4; ni++)
      bfr[ni] = *reinterpret_cast<const bf16x8*>(&Bs[(wc * 64 + ni * 16 + l15) * 32 + g * 8]);
#pragma unroll
    for (int mi = 0; mi < 4; mi++)
#pragma unroll
      for (int ni = 0; ni < 4; ni++)
        acc[mi][ni] = mfma16(af[mi], bfr[ni], acc[mi][ni]);
  }

  float bv[4];
#pragma unroll
  for (int ni = 0; ni < 4; ni++) bv[ni] = bias[n0 + wc * 64 + ni * 16 + l15];

  if (mode == 2) {
    float* out = (float*)outp;
#pragma unroll
    for (int mi = 0; mi < 4; mi++)
#pragma unroll
      for (int ni = 0; ni < 4; ni++)
#pragma unroll
        for (int r = 0; r < 4; r++) {
          int gm = m0 + wr * 64 + mi * 16 + g * 4 + r;
          int gn = n0 + wc * 64 + ni * 16 + l15;
          out[(size_t)gm * N + gn] = acc[mi][ni][r] + bv[ni];
        }
  } else {
    u16* out = (u16*)outp;
#pragma unroll
    for (int mi = 0; mi < 4; mi++)
#pragma unroll
      for (int ni = 0; ni < 4; ni++)
#pragma unroll
        for (int r = 0; r < 4; r++) {
          int gm = m0 + wr * 64 + mi * 16 + g * 4 + r;
          int gn = n0 + wc * 64 + ni * 16 + l15;
          int bb = gm >> 11, sq = gm & (SEQ - 1);
          int hh = gn >> 6, d = gn & 63;
          size_t off = (mode == 0)
              ? (((size_t)(bb * NH + hh) * SEQ + sq) * HD + d)
              : (((size_t)(bb * NH + hh) * HD + d) * SEQ + sq);
          out[off] = f2bf(acc[mi][ni][r] + bv[ni]);
        }
  }
}

// Flash attention, causal. Grid (S/64, H, B), 4 waves/block; block owns q rows
// [qb*64, qb*64+64), wave w the 16-row sub-tile. K/V^T staged in swizzled LDS,
// double-buffered, 1 barrier/iter. Swapped QK^T -> per-lane softmax; P in regs.
__global__ __launch_bounds__(256, 4) void attn_kernel(
    const u16* __restrict__ Q, const u16* __restrict__ Kt,
    const u16* __restrict__ Vt, u16* __restrict__ Y)
{
  __shared__ u16 smK[2][4096];  // [buf][64 keys][64 d]   (swizzled slots)
  __shared__ u16 smV[2][4096];  // [buf][64 d][64 keys]   (swizzled slots)
  const int tid = threadIdx.x;
  const int lane = tid & 63, w = tid >> 6;
  const int l15 = lane & 15, g = lane >> 4;
  const int h = blockIdx.y, b = blockIdx.z;
  const int qb = blockIdx.x;
  const int q0 = qb * 64 + w * 16;
  const int qg = q0 + l15;
  const int xs = l15 & 7;  // read-side XOR

  const size_t bh = (size_t)(b * NH + h);
  const u16* Qp = Q + bh * SEQ * HD;
  const u16* Kp = Kt + bh * SEQ * HD;
  const u16* Vp = Vt + bh * HD * SEQ;  // [d][s]

  // staging indices for this thread (2 x 16B per tile per iteration)
  int srow[2], sslot[2];
#pragma unroll
  for (int it = 0; it < 2; it++) {
    int idx = it * 256 + tid;
    srow[it] = idx >> 3;
    sslot[it] = (idx & 7) ^ (srow[it] & 7);  // pre-swizzled global source slot
  }

  auto stage = [&](int buf, int kt) {
#pragma unroll
    for (int it = 0; it < 2; it++) {
      int idx = it * 256 + tid;
      gload16(Kp + (size_t)(kt + srow[it]) * HD + sslot[it] * 8, &smK[buf][idx * 8]);
      gload16(Vp + (size_t)srow[it] * SEQ + kt + sslot[it] * 8, &smV[buf][idx * 8]);
    }
  };

  // Q fragments (B operand, sigma1), scale (1/8)*log2(e) folded -> exp2 domain
  const float QSC = 0.125f * 1.44269504088896f;
  bf16x8 qf[2];
#pragma unroll
  for (int hf = 0; hf < 2; hf++) {
    bf16x8 tq = *reinterpret_cast<const bf16x8*>(Qp + (size_t)qg * HD + hf * 32 + g * 8);
#pragma unroll
    for (int jj = 0; jj < 8; jj++) qf[hf][jj] = (__bf16)((float)tq[jj] * QSC);
  }

  const float NEG = -__builtin_inff();
  float m_run = NEG, l_run = 0.0f;
  f32x4 o[4] = {};  // O^T[d][q]: d = db*16 + g*4 + r, q = l15

  const int nt = qb + 1;
  stage(0, 0);

  for (int t = 0; t < nt; t++) {
    const int kt = t * 64;
    const int buf = t & 1;
    __syncthreads();  // staged buf landed (own vmcnt drained); prev reads done
    if (t + 1 < nt) stage(buf ^ 1, kt + 64);

    // ---- QK^T: S^T (log2 domain), keys = kt + sub*16 + g*4 + r, q = l15
    f32x4 sa[4];
#pragma unroll
    for (int sub = 0; sub < 4; sub++) {
      int row = sub * 16 + l15;
      bf16x8 k0 = *reinterpret_cast<const bf16x8*>(&smK[buf][row * 64 + ((0 + g) ^ xs) * 8]);
      bf16x8 k1 = *reinterpret_cast<const bf16x8*>(&smK[buf][row * 64 + ((4 + g) ^ xs) * 8]);
      f32x4 a = {0.f, 0.f, 0.f, 0.f};
      a = mfma16(k0, qf[0], a);
      a = mfma16(k1, qf[1], a);
      sa[sub] = a;
    }

    // ---- causal mask + per-q max (tree + 2 shfl)
    float p[16];
#pragma unroll
    for (int sub = 0; sub < 4; sub++)
#pragma unroll
      for (int r = 0; r < 4; r++) {
        int key = kt + sub * 16 + g * 4 + r;
        p[sub * 4 + r] = (key <= qg) ? sa[sub][r] : NEG;
      }
    float t8[8], t4[4];
#pragma unroll
    for (int i = 0; i < 8; i++) t8[i] = fmaxf(p[i], p[i + 8]);
#pragma unroll
    for (int i = 0; i < 4; i++) t4[i] = fmaxf(t8[i], t8[i + 4]);
    float tmax = fmaxf(fmaxf(t4[0], t4[2]), fmaxf(t4[1], t4[3]));
    tmax = fmaxf(tmax, __shfl_xor(tmax, 16));
    tmax = fmaxf(tmax, __shfl_xor(tmax, 32));

    // defer-max: rescale only when max grew by > 11 (log2 units)
    if (__any(tmax > m_run + 11.0f)) {
      float mnew = fmaxf(m_run, tmax);
      float fs = __builtin_amdgcn_exp2f(m_run - mnew);  // 0 when m_run=-inf
      l_run *= fs;
#pragma unroll
      for (int db = 0; db < 4; db++) o[db] *= fs;
      m_run = mnew;
    }

    // ---- P = 2^(p - m_run), sum tree, pack bf16
    float s4[4] = {0.f, 0.f, 0.f, 0.f};
    u16x4 pw[4];
#pragma unroll
    for (int i = 0; i < 16; i++) {
      float pv = __builtin_amdgcn_exp2f(p[i] - m_run);
      s4[i & 3] += pv;
      pw[i >> 2][i & 3] = f2bf(pv);
    }
    float psum = (s4[0] + s4[1]) + (s4[2] + s4[3]);
    psum += __shfl_xor(psum, 16);
    psum += __shfl_xor(psum, 32);
    l_run += psum;

    // ---- O^T += V^T * P^T; sigma2(g,j) = (j>>2)*16 + g*4 + (j&3)
#pragma unroll
    for (int half = 0; half < 2; half++) {
      u16x8 pbu;
#pragma unroll
      for (int jj = 0; jj < 4; jj++) {
        pbu[jj] = pw[2 * half][jj];
        pbu[jj + 4] = pw[2 * half + 1][jj];
      }
      bf16x8 pb = __builtin_bit_cast(bf16x8, pbu);
      const int s0 = ((4 * half + (g >> 1)) ^ xs) * 8 + 4 * (g & 1);
      const int s1 = ((4 * half + 2 + (g >> 1)) ^ xs) * 8 + 4 * (g & 1);
#pragma unroll
      for (int db = 0; db < 4; db++) {
        int vbase = (db * 16 + l15) * 64;
        u16x4 v0 = *reinterpret_cast<const u16x4*>(&smV[buf][vbase + s0]);
        u16x4 v1 = *reinterpret_cast<const u16x4*>(&smV[buf][vbase + s1]);
        u16x8 vau;
#pragma unroll
        for (int jj = 0; jj < 4; jj++) { vau[jj] = v0[jj]; vau[jj + 4] = v1[jj]; }
        bf16x8 va = __builtin_bit_cast(bf16x8, vau);
        o[db] = mfma16(va, pb, o[db]);
      }
    }
  }

  float rl = 1.0f / l_run;
#pragma unroll
  for (int db = 0; db < 4; db++) {
    u16x4 yo;
#pragma unroll
    for (int r = 0; r < 4; r++) yo[r] = f2bf(o[db][r] * rl);
    *reinterpret_cast<u16x4*>(
        Y + ((size_t)(b * SEQ) + qg) * HID + h * HD + db * 16 + g * 4) = yo;
  }
}

extern "C" void kernel_launch(void* const* d_in, const int* in_sizes, int n_in,
                              void* d_out, int out_size, void* d_ws, size_t ws_size,
                              hipStream_t stream) {
  const float* x  = (const float*)d_in[0];
  const float* Wq = (const float*)d_in[1];
  const float* bq = (const float*)d_in[2];
  const float* Wk = (const float*)d_in[3];
  const float* bk = (const float*)d_in[4];
  const float* Wv = (const float*)d_in[5];
  const float* bv = (const float*)d_in[6];
  const float* Wp = (const float*)d_in[7];
  const float* bp = (const float*)d_in[8];

  u16* ws = (u16*)d_ws;
  const size_t NX = (size_t)Bn * SEQ * HID;  // 4,194,304
  const size_t NW = (size_t)HID * HID;       // 1,048,576
  u16* xb  = ws; ws += NX;
  u16* wqb = ws; ws += NW;
  u16* wkb = ws; ws += NW;
  u16* wvb = ws; ws += NW;
  u16* wpb = ws; ws += NW;
  u16* Qb  = ws; ws += NX;
  u16* Kb  = ws; ws += NX;
  u16* Vtb = ws; ws += NX;
  u16* Yb  = ws; ws += NX;   // total ~48 MB of d_ws

  cvt_kernel<<<dim3((unsigned)(NX / 1024)), 256, 0, stream>>>(x, xb, (int)NX);
  cvt_kernel<<<dim3((unsigned)(NW / 1024)), 256, 0, stream>>>(Wq, wqb, (int)NW);
  cvt_kernel<<<dim3((unsigned)(NW / 1024)), 256, 0, stream>>>(Wk, wkb, (int)NW);
  cvt_kernel<<<dim3((unsigned)(NW / 1024)), 256, 0, stream>>>(Wv, wvb, (int)NW);
  cvt_kernel<<<dim3((unsigned)(NW / 1024)), 256, 0, stream>>>(Wp, wpb, (int)NW);

  dim3 gg(4096 / 128, 1024 / 128);
  gemm_bt<<<gg, 256, 0, stream>>>(xb, wqb, bq, Qb,  4096, 1024, 1024, 0);
  gemm_bt<<<gg, 256, 0, stream>>>(xb, wkb, bk, Kb,  4096, 1024, 1024, 0);
  gemm_bt<<<gg, 256, 0, stream>>>(xb, wvb, bv, Vtb, 4096, 1024, 1024, 1);

  attn_kernel<<<dim3(SEQ / 64, NH, Bn), 256, 0, stream>>>(Qb, Kb, Vtb, Yb);

  gemm_bt<<<gg, 256, 0, stream>>>(Yb, wpb, bp, d_out, 4096, 1024, 1024, 2);
}

// Round 4
// 121.831 us; speedup vs baseline: 2.8785x; 1.6424x over previous
//
#include <hip/hip_runtime.h>

// CausalSelfAttention: B=2 S=2048 H=16 D=64 HID=1024, fp32 in/out, bf16 MFMA compute.
//
// R4 changes vs R3:
//  - attn: pair-balanced blocks (block j does q-tiles {j, 31-j} -> 33 iters each,
//    flat occupancy, no triangular tail). Mask only on the last tile. P packed via
//    (__bf16) casts (compiler cvt_pk).
//  - QKV GEMMs fused into ONE kernel (grid 32x24 = 768 blocks = 3/CU).
//  - Wp GEMM on 64x128 tiles (grid 64x8 = 512 blocks = 2/CU).
//  - all fp32->bf16 conversions in one dispatch.
//
// MFMA layout discipline: each MFMA's operand k-slot bijection is CHOSEN and used
// consistently for BOTH its A and B operands -> result invariant to the true HW
// bijection. QK uses sigma1(g,j)=g*8+j; PV uses sigma2(g,j)=(j>>2)*16+g*4+(j&3)
// (matches QK^T C/D register layout). C/D: col = lane&15, row = (lane>>4)*4 + reg.

typedef unsigned short u16;
typedef float f32x4 __attribute__((ext_vector_type(4)));
typedef __bf16 bf16x8 __attribute__((ext_vector_type(8)));
typedef unsigned short u16x4 __attribute__((ext_vector_type(4)));
typedef unsigned short u16x8 __attribute__((ext_vector_type(8)));

constexpr int Bn = 2, SEQ = 2048, NH = 16, HD = 64, HID = 1024;
constexpr size_t NX = (size_t)Bn * SEQ * HID;  // 4,194,304
constexpr size_t NW = (size_t)HID * HID;       // 1,048,576 = 1<<20

__device__ __forceinline__ u16 f2bf(float f) {
  unsigned u = __float_as_uint(f);
  u += 0x7fff + ((u >> 16) & 1);  // RNE
  return (u16)(u >> 16);
}

__device__ __forceinline__ f32x4 mfma16(bf16x8 a, bf16x8 b, f32x4 c) {
  return __builtin_amdgcn_mfma_f32_16x16x32_bf16(a, b, c, 0, 0, 0);
}

__device__ __forceinline__ void gload16(const u16* g, u16* l) {
  __builtin_amdgcn_global_load_lds(
      (const __attribute__((address_space(1))) unsigned int*)(const void*)g,
      (__attribute__((address_space(3))) unsigned int*)(void*)l, 16, 0, 0);
}

// One dispatch converting x, Wq, Wk, Wv, Wp to bf16.
__global__ void cvt_all(const float* __restrict__ x,
                        const float* __restrict__ Wq, const float* __restrict__ Wk,
                        const float* __restrict__ Wv, const float* __restrict__ Wp,
                        u16* __restrict__ xb, u16* __restrict__ wqb, u16* __restrict__ wkb,
                        u16* __restrict__ wvb, u16* __restrict__ wpb) {
  size_t i = ((size_t)blockIdx.x * blockDim.x + threadIdx.x) * 4;
  const float* s; u16* d; size_t off;
  if (i < NX) { s = x; d = xb; off = i; }
  else {
    size_t k = i - NX;
    int id = (int)(k >> 20);
    off = k & (NW - 1);
    s = (id == 0) ? Wq : (id == 1) ? Wk : (id == 2) ? Wv : Wp;
    d = (id == 0) ? wqb : (id == 1) ? wkb : (id == 2) ? wvb : wpb;
  }
  float4 v = *reinterpret_cast<const float4*>(s + off);
  u16x4 o = {f2bf(v.x), f2bf(v.y), f2bf(v.z), f2bf(v.w)};
  *reinterpret_cast<u16x4*>(d + off) = o;
}

// Fused QKV projection: C_id = x @ W_id^T + b_id for id in {q,k,v}.
// Grid (32, 24): blockIdx.y selects 128 cols of the 3072-wide fused N dim.
// Q,K -> [b,h,s,d]; V -> [b,h,d,s] (transposed for attention PV).
__global__ __launch_bounds__(256) void qkv_gemm(
    const u16* __restrict__ A,
    const u16* __restrict__ W0, const u16* __restrict__ W1, const u16* __restrict__ W2,
    const float* __restrict__ b0, const float* __restrict__ b1, const float* __restrict__ b2,
    u16* __restrict__ out0, u16* __restrict__ out1, u16* __restrict__ out2)
{
  constexpr int K = HID;
  __shared__ u16 As[128 * 32];
  __shared__ u16 Bs[128 * 32];
  const int tid = threadIdx.x;
  const int lane = tid & 63, w = tid >> 6;
  const int wr = w >> 1, wc = w & 1;
  const int l15 = lane & 15, g = lane >> 4;
  const int m0 = blockIdx.x * 128;
  const int n0g = blockIdx.y * 128;
  const int id = n0g >> 10;
  const int n0 = n0g & (HID - 1);
  const u16* Bm = (id == 0) ? W0 : (id == 1) ? W1 : W2;
  const float* bias = (id == 0) ? b0 : (id == 1) ? b1 : b2;
  u16* out = (id == 0) ? out0 : (id == 1) ? out1 : out2;

  f32x4 acc[4][4] = {};

  for (int kt = 0; kt < K; kt += 32) {
    __syncthreads();
#pragma unroll
    for (int i = 0; i < 2; i++) {
      int chunk = tid + 256 * i;
      int r = chunk >> 2, c = (chunk & 3) << 3;
      gload16(&A[(size_t)(m0 + r) * K + kt + c], &As[(size_t)chunk * 8]);
      gload16(&Bm[(size_t)(n0 + r) * K + kt + c], &Bs[(size_t)chunk * 8]);
    }
    __syncthreads();
    bf16x8 af[4], bfr[4];
#pragma unroll
    for (int mi = 0; mi < 4; mi++)
      af[mi] = *reinterpret_cast<const bf16x8*>(&As[(wr * 64 + mi * 16 + l15) * 32 + g * 8]);
#pragma unroll
    for (int ni = 0; ni < 4; ni++)
      bfr[ni] = *reinterpret_cast<const bf16x8*>(&Bs[(wc * 64 + ni * 16 + l15) * 32 + g * 8]);
#pragma unroll
    for (int mi = 0; mi < 4; mi++)
#pragma unroll
      for (int ni = 0; ni < 4; ni++)
        acc[mi][ni] = mfma16(af[mi], bfr[ni], acc[mi][ni]);
  }

  float bv[4];
#pragma unroll
  for (int ni = 0; ni < 4; ni++) bv[ni] = bias[n0 + wc * 64 + ni * 16 + l15];

#pragma unroll
  for (int mi = 0; mi < 4; mi++)
#pragma unroll
    for (int ni = 0; ni < 4; ni++)
#pragma unroll
      for (int r = 0; r < 4; r++) {
        int gm = m0 + wr * 64 + mi * 16 + g * 4 + r;
        int gn = n0 + wc * 64 + ni * 16 + l15;
        int bb = gm >> 11, sq = gm & (SEQ - 1);
        int hh = gn >> 6, d = gn & 63;
        size_t off = (id == 2)
            ? (((size_t)(bb * NH + hh) * HD + d) * SEQ + sq)     // V^T
            : (((size_t)(bb * NH + hh) * SEQ + sq) * HD + d);    // Q, K
        out[off] = f2bf(acc[mi][ni][r] + bv[ni]);
      }
}

// Output projection: out = Y @ Wp^T + bp, fp32. 64x128 tiles, grid (64, 8).
__global__ __launch_bounds__(256) void gemm_out(
    const u16* __restrict__ A, const u16* __restrict__ Bm,
    const float* __restrict__ bias, float* __restrict__ out)
{
  constexpr int K = HID, N = HID;
  __shared__ u16 As[64 * 32];
  __shared__ u16 Bs[128 * 32];
  const int tid = threadIdx.x;
  const int lane = tid & 63, w = tid >> 6;
  const int l15 = lane & 15, g = lane >> 4;
  const int m0 = blockIdx.x * 64, n0 = blockIdx.y * 128;

  f32x4 acc[4][2] = {};

  for (int kt = 0; kt < K; kt += 32) {
    __syncthreads();
    {
      int r = tid >> 2, c = (tid & 3) << 3;
      gload16(&A[(size_t)(m0 + r) * K + kt + c], &As[(size_t)tid * 8]);
    }
#pragma unroll
    for (int i = 0; i < 2; i++) {
      int chunk = tid + 256 * i;
      int r = chunk >> 2, c = (chunk & 3) << 3;
      gload16(&Bm[(size_t)(n0 + r) * K + kt + c], &Bs[(size_t)chunk * 8]);
    }
    __syncthreads();
    bf16x8 af[4], bfr[2];
#pragma unroll
    for (int mi = 0; mi < 4; mi++)
      af[mi] = *reinterpret_cast<const bf16x8*>(&As[(mi * 16 + l15) * 32 + g * 8]);
#pragma unroll
    for (int ni = 0; ni < 2; ni++)
      bfr[ni] = *reinterpret_cast<const bf16x8*>(&Bs[(w * 32 + ni * 16 + l15) * 32 + g * 8]);
#pragma unroll
    for (int mi = 0; mi < 4; mi++)
#pragma unroll
      for (int ni = 0; ni < 2; ni++)
        acc[mi][ni] = mfma16(af[mi], bfr[ni], acc[mi][ni]);
  }

  float bv[2];
#pragma unroll
  for (int ni = 0; ni < 2; ni++) bv[ni] = bias[n0 + w * 32 + ni * 16 + l15];

#pragma unroll
  for (int mi = 0; mi < 4; mi++)
#pragma unroll
    for (int ni = 0; ni < 2; ni++)
#pragma unroll
      for (int r = 0; r < 4; r++) {
        int gm = m0 + mi * 16 + g * 4 + r;
        int gn = n0 + w * 32 + ni * 16 + l15;
        out[(size_t)gm * N + gn] = acc[mi][ni][r] + bv[ni];
      }
}

// Flash attention, causal. Grid (16, H, B); block j processes q-tiles {j, 31-j}
// (33 iterations total -> flat occupancy). 4 waves/block, wave w owns 16 q rows.
// K/V^T staged in swizzled LDS, double-buffered, 1 barrier/iter. Swapped QK^T ->
// per-lane softmax; P stays in registers (sigma2). Mask only on the last tile.
__global__ __launch_bounds__(256, 4) void attn_kernel(
    const u16* __restrict__ Q, const u16* __restrict__ Kt,
    const u16* __restrict__ Vt, u16* __restrict__ Y)
{
  __shared__ u16 smK[2][4096];  // [buf][64 keys][64 d]   (swizzled slots)
  __shared__ u16 smV[2][4096];  // [buf][64 d][64 keys]   (swizzled slots)
  const int tid = threadIdx.x;
  const int lane = tid & 63, w = tid >> 6;
  const int l15 = lane & 15, g = lane >> 4;
  const int h = blockIdx.y, b = blockIdx.z;
  const int jb = blockIdx.x;
  const int xs = l15 & 7;  // read-side XOR

  const size_t bh = (size_t)(b * NH + h);
  const u16* Qp = Q + bh * SEQ * HD;
  const u16* Kp = Kt + bh * SEQ * HD;
  const u16* Vp = Vt + bh * HD * SEQ;  // [d][s]

  int srow[2], sslot[2];
#pragma unroll
  for (int it = 0; it < 2; it++) {
    int idx = it * 256 + tid;
    srow[it] = idx >> 3;
    sslot[it] = (idx & 7) ^ (srow[it] & 7);  // pre-swizzled global source slot
  }
  auto stage = [&](int buf, int kt) {
#pragma unroll
    for (int it = 0; it < 2; it++) {
      int idx = it * 256 + tid;
      gload16(Kp + (size_t)(kt + srow[it]) * HD + sslot[it] * 8, &smK[buf][idx * 8]);
      gload16(Vp + (size_t)srow[it] * SEQ + kt + sslot[it] * 8, &smV[buf][idx * 8]);
    }
  };

  const float QSC = 0.125f * 1.44269504088896f;  // 1/sqrt(64) * log2(e)
  const float NEG = -__builtin_inff();

  for (int pi = 0; pi < 2; pi++) {
    const int tile = pi ? (31 - jb) : jb;
    const int nt = tile + 1;
    const int q0 = tile * 64 + w * 16;
    const int qg = q0 + l15;

    __syncthreads();  // previous tile's readers done before overwriting buf 0
    stage(0, 0);

    bf16x8 qf[2];
#pragma unroll
    for (int hf = 0; hf < 2; hf++) {
      bf16x8 tq = *reinterpret_cast<const bf16x8*>(Qp + (size_t)qg * HD + hf * 32 + g * 8);
#pragma unroll
      for (int jj = 0; jj < 8; jj++) qf[hf][jj] = (__bf16)((float)tq[jj] * QSC);
    }

    float m_run = NEG, l_run = 0.0f;
    f32x4 o[4] = {};  // O^T[d][q]: d = db*16 + g*4 + r, q = l15

    for (int t = 0; t < nt; t++) {
      const int kt = t * 64;
      const int buf = t & 1;
      __syncthreads();  // staged buf landed; prev buf's readers done
      if (t + 1 < nt) stage(buf ^ 1, kt + 64);

      // ---- QK^T: S^T (log2 domain), key = kt + sub*16 + g*4 + r, q = l15
      f32x4 sa[4];
#pragma unroll
      for (int sub = 0; sub < 4; sub++) {
        int row = sub * 16 + l15;
        bf16x8 k0 = *reinterpret_cast<const bf16x8*>(&smK[buf][row * 64 + ((0 + g) ^ xs) * 8]);
        bf16x8 k1 = *reinterpret_cast<const bf16x8*>(&smK[buf][row * 64 + ((4 + g) ^ xs) * 8]);
        f32x4 a = {0.f, 0.f, 0.f, 0.f};
        a = mfma16(k0, qf[0], a);
        a = mfma16(k1, qf[1], a);
        sa[sub] = a;
      }

      // ---- causal mask only on last tile
      float p[16];
      if (t == nt - 1) {
#pragma unroll
        for (int sub = 0; sub < 4; sub++)
#pragma unroll
          for (int r = 0; r < 4; r++) {
            int key = kt + sub * 16 + g * 4 + r;
            p[sub * 4 + r] = (key <= qg) ? sa[sub][r] : NEG;
          }
      } else {
#pragma unroll
        for (int sub = 0; sub < 4; sub++)
#pragma unroll
          for (int r = 0; r < 4; r++) p[sub * 4 + r] = sa[sub][r];
      }

      // ---- per-q max (tree + 2 shfl)
      float t8[8], t4[4];
#pragma unroll
      for (int i = 0; i < 8; i++) t8[i] = fmaxf(p[i], p[i + 8]);
#pragma unroll
      for (int i = 0; i < 4; i++) t4[i] = fmaxf(t8[i], t8[i + 4]);
      float tmax = fmaxf(fmaxf(t4[0], t4[2]), fmaxf(t4[1], t4[3]));
      tmax = fmaxf(tmax, __shfl_xor(tmax, 16));
      tmax = fmaxf(tmax, __shfl_xor(tmax, 32));

      // defer-max: rescale only when max grew by > 11 (log2 units)
      if (__any(tmax > m_run + 11.0f)) {
        float mnew = fmaxf(m_run, tmax);
        float fs = __builtin_amdgcn_exp2f(m_run - mnew);  // 0 when m_run=-inf
        l_run *= fs;
#pragma unroll
        for (int db = 0; db < 4; db++) o[db] *= fs;
        m_run = mnew;
      }

      // ---- P = 2^(p - m_run); sum tree; pack via compiler cvt_pk
      float pe[16];
      float s4[4] = {0.f, 0.f, 0.f, 0.f};
#pragma unroll
      for (int i = 0; i < 16; i++) {
        pe[i] = __builtin_amdgcn_exp2f(p[i] - m_run);
        s4[i & 3] += pe[i];
      }
      float psum = (s4[0] + s4[1]) + (s4[2] + s4[3]);
      psum += __shfl_xor(psum, 16);
      psum += __shfl_xor(psum, 32);
      l_run += psum;

      // ---- O^T += V^T * P^T; sigma2(g,j) = (j>>2)*16 + g*4 + (j&3)
#pragma unroll
      for (int half = 0; half < 2; half++) {
        bf16x8 pb;
#pragma unroll
        for (int jj = 0; jj < 8; jj++) pb[jj] = (__bf16)pe[8 * half + jj];
        const int s0 = ((4 * half + (g >> 1)) ^ xs) * 8 + 4 * (g & 1);
        const int s1 = ((4 * half + 2 + (g >> 1)) ^ xs) * 8 + 4 * (g & 1);
#pragma unroll
        for (int db = 0; db < 4; db++) {
          int vbase = (db * 16 + l15) * 64;
          u16x4 v0 = *reinterpret_cast<const u16x4*>(&smV[buf][vbase + s0]);
          u16x4 v1 = *reinterpret_cast<const u16x4*>(&smV[buf][vbase + s1]);
          u16x8 vau;
#pragma unroll
          for (int jj = 0; jj < 4; jj++) { vau[jj] = v0[jj]; vau[jj + 4] = v1[jj]; }
          bf16x8 va = __builtin_bit_cast(bf16x8, vau);
          o[db] = mfma16(va, pb, o[db]);
        }
      }
    }

    float rl = 1.0f / l_run;
#pragma unroll
    for (int db = 0; db < 4; db++) {
      u16x4 yo;
#pragma unroll
      for (int r = 0; r < 4; r++) yo[r] = f2bf(o[db][r] * rl);
      *reinterpret_cast<u16x4*>(
          Y + ((size_t)(b * SEQ) + qg) * HID + h * HD + db * 16 + g * 4) = yo;
    }
  }
}

extern "C" void kernel_launch(void* const* d_in, const int* in_sizes, int n_in,
                              void* d_out, int out_size, void* d_ws, size_t ws_size,
                              hipStream_t stream) {
  const float* x  = (const float*)d_in[0];
  const float* Wq = (const float*)d_in[1];
  const float* bq = (const float*)d_in[2];
  const float* Wk = (const float*)d_in[3];
  const float* bk = (const float*)d_in[4];
  const float* Wv = (const float*)d_in[5];
  const float* bv = (const float*)d_in[6];
  const float* Wp = (const float*)d_in[7];
  const float* bp = (const float*)d_in[8];

  u16* ws = (u16*)d_ws;
  u16* xb  = ws; ws += NX;
  u16* wqb = ws; ws += NW;
  u16* wkb = ws; ws += NW;
  u16* wvb = ws; ws += NW;
  u16* wpb = ws; ws += NW;
  u16* Qb  = ws; ws += NX;
  u16* Kb  = ws; ws += NX;
  u16* Vtb = ws; ws += NX;
  u16* Yb  = ws; ws += NX;   // total ~48 MB of d_ws

  const unsigned cvtBlocks = (unsigned)((NX + 4 * NW) / 4 / 256);  // 8192
  cvt_all<<<cvtBlocks, 256, 0, stream>>>(x, Wq, Wk, Wv, Wp, xb, wqb, wkb, wvb, wpb);

  qkv_gemm<<<dim3(32, 24), 256, 0, stream>>>(xb, wqb, wkb, wvb, bq, bk, bv, Qb, Kb, Vtb);

  attn_kernel<<<dim3(16, NH, Bn), 256, 0, stream>>>(Qb, Kb, Vtb, Yb);

  gemm_out<<<dim3(64, 8), 256, 0, stream>>>(Yb, wpb, bp, (float*)d_out);
}

// Round 5
// 118.923 us; speedup vs baseline: 2.9488x; 1.0245x over previous
//
#include <hip/hip_runtime.h>

// CausalSelfAttention: B=2 S=2048 H=16 D=64 HID=1024, fp32 in/out, bf16 MFMA compute.
//
// R5 changes vs R4 (all latency-oriented):
//  - attn: triple-buffered K/V LDS, depth-2 prefetch, counted s_waitcnt vmcnt(4) +
//    raw s_barrier (never drain in-flight prefetch); XCD-pinned (b,h) via 1D grid
//    decode so K/V stay L2-resident per XCD.
//  - qkv/out GEMMs: 2-phase double-buffered LDS (stage t+1 issued right after the
//    single per-K-step barrier; the barrier's vmcnt(0) lands after a full compute
//    phase) -> 1 barrier/K-step, latency hidden. Weight panels XCD-pinned via grid
//    ordering (x = n-panel).
//  - qkv V^T epilogue: transpose through swizzled LDS, 16B coalesced stores along s
//    (was 2B/lane scatter at 4KB stride).
//
// MFMA layout discipline: each MFMA's operand k-slot bijection is CHOSEN and used
// consistently for BOTH its A and B operands -> result invariant to the true HW
// bijection. QK uses sigma1(g,j)=g*8+j; PV uses sigma2(g,j)=(j>>2)*16+g*4+(j&3)
// (matches QK^T C/D register layout). C/D: col = lane&15, row = (lane>>4)*4 + reg.

typedef unsigned short u16;
typedef float f32x4 __attribute__((ext_vector_type(4)));
typedef __bf16 bf16x8 __attribute__((ext_vector_type(8)));
typedef unsigned short u16x4 __attribute__((ext_vector_type(4)));
typedef unsigned short u16x8 __attribute__((ext_vector_type(8)));

constexpr int Bn = 2, SEQ = 2048, NH = 16, HD = 64, HID = 1024;
constexpr size_t NX = (size_t)Bn * SEQ * HID;  // 4,194,304
constexpr size_t NW = (size_t)HID * HID;       // 1,048,576 = 1<<20

__device__ __forceinline__ u16 f2bf(float f) {
  unsigned u = __float_as_uint(f);
  u += 0x7fff + ((u >> 16) & 1);  // RNE
  return (u16)(u >> 16);
}

__device__ __forceinline__ f32x4 mfma16(bf16x8 a, bf16x8 b, f32x4 c) {
  return __builtin_amdgcn_mfma_f32_16x16x32_bf16(a, b, c, 0, 0, 0);
}

__device__ __forceinline__ void gload16(const u16* g, u16* l) {
  __builtin_amdgcn_global_load_lds(
      (const __attribute__((address_space(1))) unsigned int*)(const void*)g,
      (__attribute__((address_space(3))) unsigned int*)(void*)l, 16, 0, 0);
}

// One dispatch converting x, Wq, Wk, Wv, Wp to bf16.
__global__ void cvt_all(const float* __restrict__ x,
                        const float* __restrict__ Wq, const float* __restrict__ Wk,
                        const float* __restrict__ Wv, const float* __restrict__ Wp,
                        u16* __restrict__ xb, u16* __restrict__ wqb, u16* __restrict__ wkb,
                        u16* __restrict__ wvb, u16* __restrict__ wpb) {
  size_t i = ((size_t)blockIdx.x * blockDim.x + threadIdx.x) * 4;
  const float* s; u16* d; size_t off;
  if (i < NX) { s = x; d = xb; off = i; }
  else {
    size_t k = i - NX;
    int id = (int)(k >> 20);
    off = k & (NW - 1);
    s = (id == 0) ? Wq : (id == 1) ? Wk : (id == 2) ? Wv : Wp;
    d = (id == 0) ? wqb : (id == 1) ? wkb : (id == 2) ? wvb : wpb;
  }
  float4 v = *reinterpret_cast<const float4*>(s + off);
  u16x4 o = {f2bf(v.x), f2bf(v.y), f2bf(v.z), f2bf(v.w)};
  *reinterpret_cast<u16x4*>(d + off) = o;
}

// Fused QKV projection: grid (24 n-panels, 32 m-tiles); x-fastest dispatch ->
// weight panel x pinned to XCD x&7 (3 panels/XCD L2-resident).
// Q,K -> [b,h,s,d]; V -> [b,h,d,s] via LDS transpose epilogue.
__global__ __launch_bounds__(256) void qkv_gemm(
    const u16* __restrict__ A,
    const u16* __restrict__ W0, const u16* __restrict__ W1, const u16* __restrict__ W2,
    const float* __restrict__ b0, const float* __restrict__ b1, const float* __restrict__ b2,
    u16* __restrict__ out0, u16* __restrict__ out1, u16* __restrict__ out2)
{
  constexpr int K = HID;
  __shared__ u16 smem[16384];  // As[2]=smem[0..8191], Bs[2]=smem[8192..16383]; epilogue reuse 32KB
  const int tid = threadIdx.x;
  const int lane = tid & 63, w = tid >> 6;
  const int wr = w >> 1, wc = w & 1;
  const int l15 = lane & 15, g = lane >> 4;
  const int m0 = blockIdx.y * 128;
  const int n0g = blockIdx.x * 128;
  const int id = n0g >> 10;
  const int n0 = n0g & (HID - 1);
  const u16* Bm = (id == 0) ? W0 : (id == 1) ? W1 : W2;
  const float* bias = (id == 0) ? b0 : (id == 1) ? b1 : b2;

  auto stage = [&](int buf, int kt) {
#pragma unroll
    for (int i = 0; i < 2; i++) {
      int chunk = tid + 256 * i;
      int r = chunk >> 2, c = (chunk & 3) << 3;
      gload16(&A[(size_t)(m0 + r) * K + kt + c], &smem[buf * 4096 + chunk * 8]);
      gload16(&Bm[(size_t)(n0 + r) * K + kt + c], &smem[8192 + buf * 4096 + chunk * 8]);
    }
  };

  f32x4 acc[4][4] = {};
  stage(0, 0);

  for (int ki = 0; ki < 32; ki++) {
    const int buf = ki & 1;
    __syncthreads();  // vmcnt(0): stage(ki) landed (issued a full compute phase ago)
    if (ki + 1 < 32) stage(buf ^ 1, (ki + 1) * 32);
    const u16* As = &smem[buf * 4096];
    const u16* Bs = &smem[8192 + buf * 4096];
    bf16x8 af[4], bfr[4];
#pragma unroll
    for (int mi = 0; mi < 4; mi++)
      af[mi] = *reinterpret_cast<const bf16x8*>(&As[(wr * 64 + mi * 16 + l15) * 32 + g * 8]);
#pragma unroll
    for (int ni = 0; ni < 4; ni++)
      bfr[ni] = *reinterpret_cast<const bf16x8*>(&Bs[(wc * 64 + ni * 16 + l15) * 32 + g * 8]);
#pragma unroll
    for (int mi = 0; mi < 4; mi++)
#pragma unroll
      for (int ni = 0; ni < 4; ni++)
        acc[mi][ni] = mfma16(af[mi], bfr[ni], acc[mi][ni]);
  }

  float bv[4];
#pragma unroll
  for (int ni = 0; ni < 4; ni++) bv[ni] = bias[n0 + wc * 64 + ni * 16 + l15];

  if (id == 2) {
    // V^T: transpose 128(sq) x 128(d) tile through swizzled LDS, store along s.
    __syncthreads();  // K-loop LDS reads done everywhere; reuse smem
#pragma unroll
    for (int mi = 0; mi < 4; mi++)
#pragma unroll
      for (int ni = 0; ni < 4; ni++) {
        u16x4 pk;
#pragma unroll
        for (int r = 0; r < 4; r++) pk[r] = f2bf(acc[mi][ni][r] + bv[ni]);
        int d_loc = wc * 64 + ni * 16 + l15;
        int sq_base = wr * 64 + mi * 16 + g * 4;
        *reinterpret_cast<u16x4*>(
            &smem[d_loc * 128 + (sq_base ^ ((d_loc & 7) << 4))]) = pk;
      }
    __syncthreads();
    const int bb = m0 >> 11;
    const int sq0 = m0 & (SEQ - 1);
#pragma unroll
    for (int i = 0; i < 8; i++) {
      int chunk = tid + 256 * i;           // 0..2047
      int d_loc = chunk >> 4;              // 0..127
      int sqc = (chunk & 15) << 3;         // 0..120, step 8
      u16x8 val = *reinterpret_cast<const u16x8*>(
          &smem[d_loc * 128 + (sqc ^ ((d_loc & 7) << 4))]);
      int gn = n0 + d_loc;
      int hh = gn >> 6, dd = gn & 63;
      *reinterpret_cast<u16x8*>(
          &out2[((size_t)(bb * NH + hh) * HD + dd) * SEQ + sq0 + sqc]) = val;
    }
  } else {
    u16* out = (id == 0) ? out0 : out1;
#pragma unroll
    for (int mi = 0; mi < 4; mi++)
#pragma unroll
      for (int ni = 0; ni < 4; ni++)
#pragma unroll
        for (int r = 0; r < 4; r++) {
          int gm = m0 + wr * 64 + mi * 16 + g * 4 + r;
          int gn = n0 + wc * 64 + ni * 16 + l15;
          int bb = gm >> 11, sq = gm & (SEQ - 1);
          int hh = gn >> 6, d = gn & 63;
          out[((size_t)(bb * NH + hh) * SEQ + sq) * HD + d] = f2bf(acc[mi][ni][r] + bv[ni]);
        }
  }
}

// Output projection: out = Y @ Wp^T + bp, fp32. 64(M)x128(N) tiles, grid (8, 64):
// weight panel x pinned to XCD x (exactly one 256KB panel per XCD).
__global__ __launch_bounds__(256) void gemm_out(
    const u16* __restrict__ A, const u16* __restrict__ Bm,
    const float* __restrict__ bias, float* __restrict__ out)
{
  constexpr int K = HID, N = HID;
  __shared__ u16 As[2][64 * 32];
  __shared__ u16 Bs[2][128 * 32];
  const int tid = threadIdx.x;
  const int lane = tid & 63, w = tid >> 6;
  const int l15 = lane & 15, g = lane >> 4;
  const int m0 = blockIdx.y * 64, n0 = blockIdx.x * 128;

  auto stage = [&](int buf, int kt) {
    {
      int r = tid >> 2, c = (tid & 3) << 3;
      gload16(&A[(size_t)(m0 + r) * K + kt + c], &As[buf][tid * 8]);
    }
#pragma unroll
    for (int i = 0; i < 2; i++) {
      int chunk = tid + 256 * i;
      int r = chunk >> 2, c = (chunk & 3) << 3;
      gload16(&Bm[(size_t)(n0 + r) * K + kt + c], &Bs[buf][chunk * 8]);
    }
  };

  f32x4 acc[4][2] = {};
  stage(0, 0);

  for (int ki = 0; ki < 32; ki++) {
    const int buf = ki & 1;
    __syncthreads();
    if (ki + 1 < 32) stage(buf ^ 1, (ki + 1) * 32);
    bf16x8 af[4], bfr[2];
#pragma unroll
    for (int mi = 0; mi < 4; mi++)
      af[mi] = *reinterpret_cast<const bf16x8*>(&As[buf][(mi * 16 + l15) * 32 + g * 8]);
#pragma unroll
    for (int ni = 0; ni < 2; ni++)
      bfr[ni] = *reinterpret_cast<const bf16x8*>(&Bs[buf][(w * 32 + ni * 16 + l15) * 32 + g * 8]);
#pragma unroll
    for (int mi = 0; mi < 4; mi++)
#pragma unroll
      for (int ni = 0; ni < 2; ni++)
        acc[mi][ni] = mfma16(af[mi], bfr[ni], acc[mi][ni]);
  }

  float bv[2];
#pragma unroll
  for (int ni = 0; ni < 2; ni++) bv[ni] = bias[n0 + w * 32 + ni * 16 + l15];

#pragma unroll
  for (int mi = 0; mi < 4; mi++)
#pragma unroll
    for (int ni = 0; ni < 2; ni++)
#pragma unroll
      for (int r = 0; r < 4; r++) {
        int gm = m0 + mi * 16 + g * 4 + r;
        int gn = n0 + w * 32 + ni * 16 + l15;
        out[(size_t)gm * N + gn] = acc[mi][ni][r] + bv[ni];
      }
}

// Flash attention, causal. 1D grid 512: bid -> (xcd-pinned bh, pair-block jb).
// Block j does q-tiles {j, 31-j} (33 iters, flat). Triple-buffered K/V LDS,
// depth-2 prefetch, counted vmcnt + raw s_barrier. Swapped QK^T; P in registers.
__global__ __launch_bounds__(256) void attn_kernel(
    const u16* __restrict__ Q, const u16* __restrict__ Kt,
    const u16* __restrict__ Vt, u16* __restrict__ Y)
{
  __shared__ u16 smK[3][4096];  // [buf][64 keys][64 d]   (swizzled slots)
  __shared__ u16 smV[3][4096];  // [buf][64 d][64 keys]   (swizzled slots)
  const int tid = threadIdx.x;
  const int lane = tid & 63, w = tid >> 6;
  const int l15 = lane & 15, g = lane >> 4;
  const int bid = blockIdx.x;                    // 0..511
  const int xcd = bid & 7, kk = bid >> 3;        // kk 0..63
  const int bh = xcd * 4 + (kk >> 4);            // pin 4 bh per XCD
  const int jb = kk & 15;
  const int b = bh >> 4, h = bh & 15;
  const int xs = l15 & 7;  // read-side XOR

  const size_t bhs = (size_t)bh;
  const u16* Qp = Q + bhs * SEQ * HD;
  const u16* Kp = Kt + bhs * SEQ * HD;
  const u16* Vp = Vt + bhs * HD * SEQ;  // [d][s]

  int srow[2], sslot[2];
#pragma unroll
  for (int it = 0; it < 2; it++) {
    int idx = it * 256 + tid;
    srow[it] = idx >> 3;
    sslot[it] = (idx & 7) ^ (srow[it] & 7);  // pre-swizzled global source slot
  }
  auto stage = [&](int buf, int kt) {
#pragma unroll
    for (int it = 0; it < 2; it++) {
      int idx = it * 256 + tid;
      gload16(Kp + (size_t)(kt + srow[it]) * HD + sslot[it] * 8, &smK[buf][idx * 8]);
      gload16(Vp + (size_t)srow[it] * SEQ + kt + sslot[it] * 8, &smV[buf][idx * 8]);
    }
  };

  const float QSC = 0.125f * 1.44269504088896f;  // 1/sqrt(64) * log2(e)
  const float NEG = -__builtin_inff();

  for (int pi = 0; pi < 2; pi++) {
    const int tile = pi ? (31 - jb) : jb;
    const int nt = tile + 1;
    const int q0 = tile * 64 + w * 16;
    const int qg = q0 + l15;

    __syncthreads();  // previous tile's LDS readers done before restaging buf 0/1

    // Q loads first so their implicit wait doesn't drain the stages
    bf16x8 tq0 = *reinterpret_cast<const bf16x8*>(Qp + (size_t)qg * HD + g * 8);
    bf16x8 tq1 = *reinterpret_cast<const bf16x8*>(Qp + (size_t)qg * HD + 32 + g * 8);

    stage(0, 0);
    if (nt > 1) stage(1, 64);

    bf16x8 qf[2];
#pragma unroll
    for (int jj = 0; jj < 8; jj++) {
      qf[0][jj] = (__bf16)((float)tq0[jj] * QSC);
      qf[1][jj] = (__bf16)((float)tq1[jj] * QSC);
    }

    float m_run = NEG, l_run = 0.0f;
    f32x4 o[4] = {};  // O^T[d][q]: d = db*16 + g*4 + r, q = l15

    for (int t = 0; t < nt; t++) {
      const int kt = t * 64;
      const u16* K_ = smK[t % 3];
      const u16* V_ = smV[t % 3];
      // stage(t) must be landed; stage(t+1)'s 4 loads may stay in flight
      if (t + 1 < nt) { asm volatile("s_waitcnt vmcnt(4)" ::: "memory"); }
      else            { asm volatile("s_waitcnt vmcnt(0)" ::: "memory"); }
      __builtin_amdgcn_s_barrier();
      if (t + 2 < nt) stage((t + 2) % 3, kt + 128);

      // ---- QK^T: S^T (log2 domain), key = kt + sub*16 + g*4 + r, q = l15
      f32x4 sa[4];
#pragma unroll
      for (int sub = 0; sub < 4; sub++) {
        int row = sub * 16 + l15;
        bf16x8 k0 = *reinterpret_cast<const bf16x8*>(&K_[row * 64 + ((0 + g) ^ xs) * 8]);
        bf16x8 k1 = *reinterpret_cast<const bf16x8*>(&K_[row * 64 + ((4 + g) ^ xs) * 8]);
        f32x4 a = {0.f, 0.f, 0.f, 0.f};
        a = mfma16(k0, qf[0], a);
        a = mfma16(k1, qf[1], a);
        sa[sub] = a;
      }

      // ---- causal mask only on the last tile
      float p[16];
      if (t == nt - 1) {
#pragma unroll
        for (int sub = 0; sub < 4; sub++)
#pragma unroll
          for (int r = 0; r < 4; r++) {
            int key = kt + sub * 16 + g * 4 + r;
            p[sub * 4 + r] = (key <= qg) ? sa[sub][r] : NEG;
          }
      } else {
#pragma unroll
        for (int sub = 0; sub < 4; sub++)
#pragma unroll
          for (int r = 0; r < 4; r++) p[sub * 4 + r] = sa[sub][r];
      }

      // ---- per-q max (tree + 2 shfl)
      float t8[8], t4[4];
#pragma unroll
      for (int i = 0; i < 8; i++) t8[i] = fmaxf(p[i], p[i + 8]);
#pragma unroll
      for (int i = 0; i < 4; i++) t4[i] = fmaxf(t8[i], t8[i + 4]);
      float tmax = fmaxf(fmaxf(t4[0], t4[2]), fmaxf(t4[1], t4[3]));
      tmax = fmaxf(tmax, __shfl_xor(tmax, 16));
      tmax = fmaxf(tmax, __shfl_xor(tmax, 32));

      // defer-max: rescale only when max grew by > 11 (log2 units)
      if (__any(tmax > m_run + 11.0f)) {
        float mnew = fmaxf(m_run, tmax);
        float fs = __builtin_amdgcn_exp2f(m_run - mnew);  // 0 when m_run=-inf
        l_run *= fs;
#pragma unroll
        for (int db = 0; db < 4; db++) o[db] *= fs;
        m_run = mnew;
      }

      // ---- P = 2^(p - m_run); sum tree; pack via compiler cvt_pk
      float pe[16];
      float s4[4] = {0.f, 0.f, 0.f, 0.f};
#pragma unroll
      for (int i = 0; i < 16; i++) {
        pe[i] = __builtin_amdgcn_exp2f(p[i] - m_run);
        s4[i & 3] += pe[i];
      }
      float psum = (s4[0] + s4[1]) + (s4[2] + s4[3]);
      psum += __shfl_xor(psum, 16);
      psum += __shfl_xor(psum, 32);
      l_run += psum;

      // ---- O^T += V^T * P^T; sigma2(g,j) = (j>>2)*16 + g*4 + (j&3)
#pragma unroll
      for (int half = 0; half < 2; half++) {
        bf16x8 pb;
#pragma unroll
        for (int jj = 0; jj < 8; jj++) pb[jj] = (__bf16)pe[8 * half + jj];
        const int s0 = ((4 * half + (g >> 1)) ^ xs) * 8 + 4 * (g & 1);
        const int s1 = ((4 * half + 2 + (g >> 1)) ^ xs) * 8 + 4 * (g & 1);
#pragma unroll
        for (int db = 0; db < 4; db++) {
          int vbase = (db * 16 + l15) * 64;
          u16x4 v0 = *reinterpret_cast<const u16x4*>(&V_[vbase + s0]);
          u16x4 v1 = *reinterpret_cast<const u16x4*>(&V_[vbase + s1]);
          u16x8 vau;
#pragma unroll
          for (int jj = 0; jj < 4; jj++) { vau[jj] = v0[jj]; vau[jj + 4] = v1[jj]; }
          bf16x8 va = __builtin_bit_cast(bf16x8, vau);
          o[db] = mfma16(va, pb, o[db]);
        }
      }
    }

    float rl = 1.0f / l_run;
#pragma unroll
    for (int db = 0; db < 4; db++) {
      u16x4 yo;
#pragma unroll
      for (int r = 0; r < 4; r++) yo[r] = f2bf(o[db][r] * rl);
      *reinterpret_cast<u16x4*>(
          Y + ((size_t)(b * SEQ) + qg) * HID + h * HD + db * 16 + g * 4) = yo;
    }
  }
}

extern "C" void kernel_launch(void* const* d_in, const int* in_sizes, int n_in,
                              void* d_out, int out_size, void* d_ws, size_t ws_size,
                              hipStream_t stream) {
  const float* x  = (const float*)d_in[0];
  const float* Wq = (const float*)d_in[1];
  const float* bq = (const float*)d_in[2];
  const float* Wk = (const float*)d_in[3];
  const float* bk = (const float*)d_in[4];
  const float* Wv = (const float*)d_in[5];
  const float* bv = (const float*)d_in[6];
  const float* Wp = (const float*)d_in[7];
  const float* bp = (const float*)d_in[8];

  u16* ws = (u16*)d_ws;
  u16* xb  = ws; ws += NX;
  u16* wqb = ws; ws += NW;
  u16* wkb = ws; ws += NW;
  u16* wvb = ws; ws += NW;
  u16* wpb = ws; ws += NW;
  u16* Qb  = ws; ws += NX;
  u16* Kb  = ws; ws += NX;
  u16* Vtb = ws; ws += NX;
  u16* Yb  = ws; ws += NX;   // total ~48 MB of d_ws

  const unsigned cvtBlocks = (unsigned)((NX + 4 * NW) / 4 / 256);  // 8192
  cvt_all<<<cvtBlocks, 256, 0, stream>>>(x, Wq, Wk, Wv, Wp, xb, wqb, wkb, wvb, wpb);

  qkv_gemm<<<dim3(24, 32), 256, 0, stream>>>(xb, wqb, wkb, wvb, bq, bk, bv, Qb, Kb, Vtb);

  attn_kernel<<<dim3(512), 256, 0, stream>>>(Qb, Kb, Vtb, Yb);

  gemm_out<<<dim3(8, 64), 256, 0, stream>>>(Yb, wpb, bp, (float*)d_out);
}

// Round 6
// 114.463 us; speedup vs baseline: 3.0637x; 1.0390x over previous
//
#include <hip/hip_runtime.h>

// CausalSelfAttention: B=2 S=2048 H=16 D=64 HID=1024, fp32 in/out, bf16 MFMA compute.
//
// R6 changes vs R5 (attn only; R5 falsified "staging-latency-bound" -> chain-latency
// bound at 2 blocks/CU):
//  - attn grid 512 -> 1024 blocks (one 64-row q-tile each), LDS 48 -> 32KB
//    (double-buffer + __syncthreads; R5 showed counted-vmcnt/depth-2 gains nothing),
//    __launch_bounds__(256,4) -> 4 blocks/CU co-resident (2x TLP).
//  - static per-CU balance: rounds (bid, bid+256, +512, +768) land on the same CU;
//    CU slot s gets tiles {24+s, 23-s, 8+s, 7-s} -> per-CU iter sum = 66 for all s.
//    XCD pinning kept (xcd = bid&7 owns bh in {4*xcd..4*xcd+3}).
//  - balanced max3-friendly max tree.
//
// MFMA layout discipline: each MFMA's operand k-slot bijection is CHOSEN and used
// consistently for BOTH its A and B operands -> result invariant to the true HW
// bijection. QK uses sigma1(g,j)=g*8+j; PV uses sigma2(g,j)=(j>>2)*16+g*4+(j&3)
// (matches QK^T C/D register layout). C/D: col = lane&15, row = (lane>>4)*4 + reg.

typedef unsigned short u16;
typedef float f32x4 __attribute__((ext_vector_type(4)));
typedef __bf16 bf16x8 __attribute__((ext_vector_type(8)));
typedef unsigned short u16x4 __attribute__((ext_vector_type(4)));
typedef unsigned short u16x8 __attribute__((ext_vector_type(8)));

constexpr int Bn = 2, SEQ = 2048, NH = 16, HD = 64, HID = 1024;
constexpr size_t NX = (size_t)Bn * SEQ * HID;  // 4,194,304
constexpr size_t NW = (size_t)HID * HID;       // 1,048,576 = 1<<20

__device__ __forceinline__ u16 f2bf(float f) {
  unsigned u = __float_as_uint(f);
  u += 0x7fff + ((u >> 16) & 1);  // RNE
  return (u16)(u >> 16);
}

__device__ __forceinline__ f32x4 mfma16(bf16x8 a, bf16x8 b, f32x4 c) {
  return __builtin_amdgcn_mfma_f32_16x16x32_bf16(a, b, c, 0, 0, 0);
}

__device__ __forceinline__ void gload16(const u16* g, u16* l) {
  __builtin_amdgcn_global_load_lds(
      (const __attribute__((address_space(1))) unsigned int*)(const void*)g,
      (__attribute__((address_space(3))) unsigned int*)(void*)l, 16, 0, 0);
}

// One dispatch converting x, Wq, Wk, Wv, Wp to bf16.
__global__ void cvt_all(const float* __restrict__ x,
                        const float* __restrict__ Wq, const float* __restrict__ Wk,
                        const float* __restrict__ Wv, const float* __restrict__ Wp,
                        u16* __restrict__ xb, u16* __restrict__ wqb, u16* __restrict__ wkb,
                        u16* __restrict__ wvb, u16* __restrict__ wpb) {
  size_t i = ((size_t)blockIdx.x * blockDim.x + threadIdx.x) * 4;
  const float* s; u16* d; size_t off;
  if (i < NX) { s = x; d = xb; off = i; }
  else {
    size_t k = i - NX;
    int id = (int)(k >> 20);
    off = k & (NW - 1);
    s = (id == 0) ? Wq : (id == 1) ? Wk : (id == 2) ? Wv : Wp;
    d = (id == 0) ? wqb : (id == 1) ? wkb : (id == 2) ? wvb : wpb;
  }
  float4 v = *reinterpret_cast<const float4*>(s + off);
  u16x4 o = {f2bf(v.x), f2bf(v.y), f2bf(v.z), f2bf(v.w)};
  *reinterpret_cast<u16x4*>(d + off) = o;
}

// Fused QKV projection: grid (24 n-panels, 32 m-tiles); x-fastest dispatch ->
// weight panel x pinned to XCD x&7 (3 panels/XCD L2-resident).
// Q,K -> [b,h,s,d]; V -> [b,h,d,s] via LDS transpose epilogue.
__global__ __launch_bounds__(256) void qkv_gemm(
    const u16* __restrict__ A,
    const u16* __restrict__ W0, const u16* __restrict__ W1, const u16* __restrict__ W2,
    const float* __restrict__ b0, const float* __restrict__ b1, const float* __restrict__ b2,
    u16* __restrict__ out0, u16* __restrict__ out1, u16* __restrict__ out2)
{
  constexpr int K = HID;
  __shared__ u16 smem[16384];  // As[2]=smem[0..8191], Bs[2]=smem[8192..16383]; epilogue reuse 32KB
  const int tid = threadIdx.x;
  const int lane = tid & 63, w = tid >> 6;
  const int wr = w >> 1, wc = w & 1;
  const int l15 = lane & 15, g = lane >> 4;
  const int m0 = blockIdx.y * 128;
  const int n0g = blockIdx.x * 128;
  const int id = n0g >> 10;
  const int n0 = n0g & (HID - 1);
  const u16* Bm = (id == 0) ? W0 : (id == 1) ? W1 : W2;
  const float* bias = (id == 0) ? b0 : (id == 1) ? b1 : b2;

  auto stage = [&](int buf, int kt) {
#pragma unroll
    for (int i = 0; i < 2; i++) {
      int chunk = tid + 256 * i;
      int r = chunk >> 2, c = (chunk & 3) << 3;
      gload16(&A[(size_t)(m0 + r) * K + kt + c], &smem[buf * 4096 + chunk * 8]);
      gload16(&Bm[(size_t)(n0 + r) * K + kt + c], &smem[8192 + buf * 4096 + chunk * 8]);
    }
  };

  f32x4 acc[4][4] = {};
  stage(0, 0);

  for (int ki = 0; ki < 32; ki++) {
    const int buf = ki & 1;
    __syncthreads();  // vmcnt(0): stage(ki) landed (issued a full compute phase ago)
    if (ki + 1 < 32) stage(buf ^ 1, (ki + 1) * 32);
    const u16* As = &smem[buf * 4096];
    const u16* Bs = &smem[8192 + buf * 4096];
    bf16x8 af[4], bfr[4];
#pragma unroll
    for (int mi = 0; mi < 4; mi++)
      af[mi] = *reinterpret_cast<const bf16x8*>(&As[(wr * 64 + mi * 16 + l15) * 32 + g * 8]);
#pragma unroll
    for (int ni = 0; ni < 4; ni++)
      bfr[ni] = *reinterpret_cast<const bf16x8*>(&Bs[(wc * 64 + ni * 16 + l15) * 32 + g * 8]);
#pragma unroll
    for (int mi = 0; mi < 4; mi++)
#pragma unroll
      for (int ni = 0; ni < 4; ni++)
        acc[mi][ni] = mfma16(af[mi], bfr[ni], acc[mi][ni]);
  }

  float bv[4];
#pragma unroll
  for (int ni = 0; ni < 4; ni++) bv[ni] = bias[n0 + wc * 64 + ni * 16 + l15];

  if (id == 2) {
    // V^T: transpose 128(sq) x 128(d) tile through swizzled LDS, store along s.
    __syncthreads();  // K-loop LDS reads done everywhere; reuse smem
#pragma unroll
    for (int mi = 0; mi < 4; mi++)
#pragma unroll
      for (int ni = 0; ni < 4; ni++) {
        u16x4 pk;
#pragma unroll
        for (int r = 0; r < 4; r++) pk[r] = f2bf(acc[mi][ni][r] + bv[ni]);
        int d_loc = wc * 64 + ni * 16 + l15;
        int sq_base = wr * 64 + mi * 16 + g * 4;
        *reinterpret_cast<u16x4*>(
            &smem[d_loc * 128 + (sq_base ^ ((d_loc & 7) << 4))]) = pk;
      }
    __syncthreads();
    const int bb = m0 >> 11;
    const int sq0 = m0 & (SEQ - 1);
#pragma unroll
    for (int i = 0; i < 8; i++) {
      int chunk = tid + 256 * i;           // 0..2047
      int d_loc = chunk >> 4;              // 0..127
      int sqc = (chunk & 15) << 3;         // 0..120, step 8
      u16x8 val = *reinterpret_cast<const u16x8*>(
          &smem[d_loc * 128 + (sqc ^ ((d_loc & 7) << 4))]);
      int gn = n0 + d_loc;
      int hh = gn >> 6, dd = gn & 63;
      *reinterpret_cast<u16x8*>(
          &out2[((size_t)(bb * NH + hh) * HD + dd) * SEQ + sq0 + sqc]) = val;
    }
  } else {
    u16* out = (id == 0) ? out0 : out1;
#pragma unroll
    for (int mi = 0; mi < 4; mi++)
#pragma unroll
      for (int ni = 0; ni < 4; ni++)
#pragma unroll
        for (int r = 0; r < 4; r++) {
          int gm = m0 + wr * 64 + mi * 16 + g * 4 + r;
          int gn = n0 + wc * 64 + ni * 16 + l15;
          int bb = gm >> 11, sq = gm & (SEQ - 1);
          int hh = gn >> 6, d = gn & 63;
          out[((size_t)(bb * NH + hh) * SEQ + sq) * HD + d] = f2bf(acc[mi][ni][r] + bv[ni]);
        }
  }
}

// Output projection: out = Y @ Wp^T + bp, fp32. 64(M)x128(N) tiles, grid (8, 64):
// weight panel x pinned to XCD x (exactly one 256KB panel per XCD).
__global__ __launch_bounds__(256) void gemm_out(
    const u16* __restrict__ A, const u16* __restrict__ Bm,
    const float* __restrict__ bias, float* __restrict__ out)
{
  constexpr int K = HID, N = HID;
  __shared__ u16 As[2][64 * 32];
  __shared__ u16 Bs[2][128 * 32];
  const int tid = threadIdx.x;
  const int lane = tid & 63, w = tid >> 6;
  const int l15 = lane & 15, g = lane >> 4;
  const int m0 = blockIdx.y * 64, n0 = blockIdx.x * 128;

  auto stage = [&](int buf, int kt) {
    {
      int r = tid >> 2, c = (tid & 3) << 3;
      gload16(&A[(size_t)(m0 + r) * K + kt + c], &As[buf][tid * 8]);
    }
#pragma unroll
    for (int i = 0; i < 2; i++) {
      int chunk = tid + 256 * i;
      int r = chunk >> 2, c = (chunk & 3) << 3;
      gload16(&Bm[(size_t)(n0 + r) * K + kt + c], &Bs[buf][chunk * 8]);
    }
  };

  f32x4 acc[4][2] = {};
  stage(0, 0);

  for (int ki = 0; ki < 32; ki++) {
    const int buf = ki & 1;
    __syncthreads();
    if (ki + 1 < 32) stage(buf ^ 1, (ki + 1) * 32);
    bf16x8 af[4], bfr[2];
#pragma unroll
    for (int mi = 0; mi < 4; mi++)
      af[mi] = *reinterpret_cast<const bf16x8*>(&As[buf][(mi * 16 + l15) * 32 + g * 8]);
#pragma unroll
    for (int ni = 0; ni < 2; ni++)
      bfr[ni] = *reinterpret_cast<const bf16x8*>(&Bs[buf][(w * 32 + ni * 16 + l15) * 32 + g * 8]);
#pragma unroll
    for (int mi = 0; mi < 4; mi++)
#pragma unroll
      for (int ni = 0; ni < 2; ni++)
        acc[mi][ni] = mfma16(af[mi], bfr[ni], acc[mi][ni]);
  }

  float bv[2];
#pragma unroll
  for (int ni = 0; ni < 2; ni++) bv[ni] = bias[n0 + w * 32 + ni * 16 + l15];

#pragma unroll
  for (int mi = 0; mi < 4; mi++)
#pragma unroll
    for (int ni = 0; ni < 2; ni++)
#pragma unroll
      for (int r = 0; r < 4; r++) {
        int gm = m0 + mi * 16 + g * 4 + r;
        int gn = n0 + w * 32 + ni * 16 + l15;
        out[(size_t)gm * N + gn] = acc[mi][ni][r] + bv[ni];
      }
}

// Flash attention, causal. Grid 1024 (all co-resident, 4 blocks/CU).
// bid -> (xcd, bh, tile) with per-CU balanced tiles {24+s, 23-s, 8+s, 7-s}
// across the 4 rounds (bid, bid+256, +512, +768) -> per-CU iter sum = 66.
// Double-buffered K/V LDS (32KB), stage-after-barrier. Swapped QK^T; P in regs.
__global__ __launch_bounds__(256, 4) void attn_kernel(
    const u16* __restrict__ Q, const u16* __restrict__ Kt,
    const u16* __restrict__ Vt, u16* __restrict__ Y)
{
  __shared__ u16 smK[2][4096];  // [buf][64 keys][64 d]   (swizzled slots)
  __shared__ u16 smV[2][4096];  // [buf][64 d][64 keys]   (swizzled slots)
  const int tid = threadIdx.x;
  const int lane = tid & 63, w = tid >> 6;
  const int l15 = lane & 15, g = lane >> 4;
  const int bid = blockIdx.x;          // 0..1023
  const int q = bid >> 8;              // round 0..3 (same CU across rounds)
  const int rr = bid & 255;
  const int xcd = rr & 7;
  const int cu = (rr >> 3) & 31;       // CU slot within XCD
  const int bh = xcd * 4 + (cu & 3);   // 4 bh pinned per XCD
  const int s = cu >> 2;               // 0..7
  int tile;
  if (q == 0) tile = 24 + s;
  else if (q == 1) tile = 23 - s;
  else if (q == 2) tile = 8 + s;
  else tile = 7 - s;
  const int b = bh >> 4, h = bh & 15;
  const int xs = l15 & 7;  // read-side XOR

  const int nt = tile + 1;
  const int q0 = tile * 64 + w * 16;
  const int qg = q0 + l15;

  const size_t bhs = (size_t)bh;
  const u16* Qp = Q + bhs * SEQ * HD;
  const u16* Kp = Kt + bhs * SEQ * HD;
  const u16* Vp = Vt + bhs * HD * SEQ;  // [d][s]

  int srow[2], sslot[2];
#pragma unroll
  for (int it = 0; it < 2; it++) {
    int idx = it * 256 + tid;
    srow[it] = idx >> 3;
    sslot[it] = (idx & 7) ^ (srow[it] & 7);  // pre-swizzled global source slot
  }
  auto stage = [&](int buf, int kt) {
#pragma unroll
    for (int it = 0; it < 2; it++) {
      int idx = it * 256 + tid;
      gload16(Kp + (size_t)(kt + srow[it]) * HD + sslot[it] * 8, &smK[buf][idx * 8]);
      gload16(Vp + (size_t)srow[it] * SEQ + kt + sslot[it] * 8, &smV[buf][idx * 8]);
    }
  };

  const float QSC = 0.125f * 1.44269504088896f;  // 1/sqrt(64) * log2(e)
  const float NEG = -__builtin_inff();

  // Q fragments (B operand, sigma1)
  bf16x8 tq0 = *reinterpret_cast<const bf16x8*>(Qp + (size_t)qg * HD + g * 8);
  bf16x8 tq1 = *reinterpret_cast<const bf16x8*>(Qp + (size_t)qg * HD + 32 + g * 8);
  stage(0, 0);
  bf16x8 qf[2];
#pragma unroll
  for (int jj = 0; jj < 8; jj++) {
    qf[0][jj] = (__bf16)((float)tq0[jj] * QSC);
    qf[1][jj] = (__bf16)((float)tq1[jj] * QSC);
  }

  float m_run = NEG, l_run = 0.0f;
  f32x4 o[4] = {};  // O^T[d][q]: d = db*16 + g*4 + r, q = l15

  for (int t = 0; t < nt; t++) {
    const int kt = t * 64;
    const int buf = t & 1;
    __syncthreads();  // stage(t) landed (issued a full iteration ago); buf^1 readers done
    if (t + 1 < nt) stage(buf ^ 1, kt + 64);
    const u16* K_ = smK[buf];
    const u16* V_ = smV[buf];

    // ---- QK^T: S^T (log2 domain), key = kt + sub*16 + g*4 + r, q = l15
    f32x4 sa[4];
#pragma unroll
    for (int sub = 0; sub < 4; sub++) {
      int row = sub * 16 + l15;
      bf16x8 k0 = *reinterpret_cast<const bf16x8*>(&K_[row * 64 + ((0 + g) ^ xs) * 8]);
      bf16x8 k1 = *reinterpret_cast<const bf16x8*>(&K_[row * 64 + ((4 + g) ^ xs) * 8]);
      f32x4 a = {0.f, 0.f, 0.f, 0.f};
      a = mfma16(k0, qf[0], a);
      a = mfma16(k1, qf[1], a);
      sa[sub] = a;
    }

    // ---- causal mask only on the last tile
    float p[16];
    if (t == nt - 1) {
#pragma unroll
      for (int sub = 0; sub < 4; sub++)
#pragma unroll
        for (int r = 0; r < 4; r++) {
          int key = kt + sub * 16 + g * 4 + r;
          p[sub * 4 + r] = (key <= qg) ? sa[sub][r] : NEG;
        }
    } else {
#pragma unroll
      for (int sub = 0; sub < 4; sub++)
#pragma unroll
        for (int r = 0; r < 4; r++) p[sub * 4 + r] = sa[sub][r];
    }

    // ---- per-q max: balanced max3-friendly tree + 2 shfl
    float a0 = fmaxf(fmaxf(p[0], p[1]), p[2]);
    float a1 = fmaxf(fmaxf(p[3], p[4]), p[5]);
    float a2 = fmaxf(fmaxf(p[6], p[7]), p[8]);
    float a3 = fmaxf(fmaxf(p[9], p[10]), p[11]);
    float a4 = fmaxf(fmaxf(p[12], p[13]), p[14]);
    float b0 = fmaxf(fmaxf(a0, a1), p[15]);
    float tmax = fmaxf(fmaxf(b0, a2), fmaxf(a3, a4));
    tmax = fmaxf(tmax, __shfl_xor(tmax, 16));
    tmax = fmaxf(tmax, __shfl_xor(tmax, 32));

    // defer-max: rescale only when max grew by > 11 (log2 units)
    if (__any(tmax > m_run + 11.0f)) {
      float mnew = fmaxf(m_run, tmax);
      float fs = __builtin_amdgcn_exp2f(m_run - mnew);  // 0 when m_run=-inf
      l_run *= fs;
#pragma unroll
      for (int db = 0; db < 4; db++) o[db] *= fs;
      m_run = mnew;
    }

    // ---- P = 2^(p - m_run); sum tree; pack via compiler cvt_pk
    float pe[16];
    float s4[4] = {0.f, 0.f, 0.f, 0.f};
#pragma unroll
    for (int i = 0; i < 16; i++) {
      pe[i] = __builtin_amdgcn_exp2f(p[i] - m_run);
      s4[i & 3] += pe[i];
    }
    float psum = (s4[0] + s4[1]) + (s4[2] + s4[3]);
    psum += __shfl_xor(psum, 16);
    psum += __shfl_xor(psum, 32);
    l_run += psum;

    // ---- O^T += V^T * P^T; sigma2(g,j) = (j>>2)*16 + g*4 + (j&3)
#pragma unroll
    for (int half = 0; half < 2; half++) {
      bf16x8 pb;
#pragma unroll
      for (int jj = 0; jj < 8; jj++) pb[jj] = (__bf16)pe[8 * half + jj];
      const int s0 = ((4 * half + (g >> 1)) ^ xs) * 8 + 4 * (g & 1);
      const int s1 = ((4 * half + 2 + (g >> 1)) ^ xs) * 8 + 4 * (g & 1);
#pragma unroll
      for (int db = 0; db < 4; db++) {
        int vbase = (db * 16 + l15) * 64;
        u16x4 v0 = *reinterpret_cast<const u16x4*>(&V_[vbase + s0]);
        u16x4 v1 = *reinterpret_cast<const u16x4*>(&V_[vbase + s1]);
        u16x8 vau;
#pragma unroll
        for (int jj = 0; jj < 4; jj++) { vau[jj] = v0[jj]; vau[jj + 4] = v1[jj]; }
        bf16x8 va = __builtin_bit_cast(bf16x8, vau);
        o[db] = mfma16(va, pb, o[db]);
      }
    }
  }

  float rl = 1.0f / l_run;
#pragma unroll
  for (int db = 0; db < 4; db++) {
    u16x4 yo;
#pragma unroll
    for (int r = 0; r < 4; r++) yo[r] = f2bf(o[db][r] * rl);
    *reinterpret_cast<u16x4*>(
        Y + ((size_t)(b * SEQ) + qg) * HID + h * HD + db * 16 + g * 4) = yo;
  }
}

extern "C" void kernel_launch(void* const* d_in, const int* in_sizes, int n_in,
                              void* d_out, int out_size, void* d_ws, size_t ws_size,
                              hipStream_t stream) {
  const float* x  = (const float*)d_in[0];
  const float* Wq = (const float*)d_in[1];
  const float* bq = (const float*)d_in[2];
  const float* Wk = (const float*)d_in[3];
  const float* bk = (const float*)d_in[4];
  const float* Wv = (const float*)d_in[5];
  const float* bv = (const float*)d_in[6];
  const float* Wp = (const float*)d_in[7];
  const float* bp = (const float*)d_in[8];

  u16* ws = (u16*)d_ws;
  u16* xb  = ws; ws += NX;
  u16* wqb = ws; ws += NW;
  u16* wkb = ws; ws += NW;
  u16* wvb = ws; ws += NW;
  u16* wpb = ws; ws += NW;
  u16* Qb  = ws; ws += NX;
  u16* Kb  = ws; ws += NX;
  u16* Vtb = ws; ws += NX;
  u16* Yb  = ws; ws += NX;   // total ~48 MB of d_ws

  const unsigned cvtBlocks = (unsigned)((NX + 4 * NW) / 4 / 256);  // 8192
  cvt_all<<<cvtBlocks, 256, 0, stream>>>(x, Wq, Wk, Wv, Wp, xb, wqb, wkb, wvb, wpb);

  qkv_gemm<<<dim3(24, 32), 256, 0, stream>>>(xb, wqb, wkb, wvb, bq, bk, bv, Qb, Kb, Vtb);

  attn_kernel<<<dim3(1024), 256, 0, stream>>>(Qb, Kb, Vtb, Yb);

  gemm_out<<<dim3(8, 64), 256, 0, stream>>>(Yb, wpb, bp, (float*)d_out);
}

// Round 7
// 114.249 us; speedup vs baseline: 3.0695x; 1.0019x over previous
//
#include <hip/hip_runtime.h>

// CausalSelfAttention: B=2 S=2048 H=16 D=64 HID=1024, fp32 in/out, bf16 MFMA compute.
//
// R7 changes vs R6 (attn inner loop only — chain surgery):
//  - Deferred l-sum: per-lane partial l (rescale multiplies it; fs is q-uniform),
//    single cross-lane reduce AFTER the key loop. Removes 2 shfl/iter.
//  - Trigger-only max: per-lane max tree + __any(local > m+11) vcc check; full
//    cross-lane max only on the (rare) trigger. Removes 2 shfl/iter from the chain.
//  - Masked last iteration peeled out of the loop (no mask branch in main body).
//  Grid/balance/staging identical to R6 (1024 blocks, 4/CU, XCD-pinned, dbuf LDS).
//
// MFMA layout discipline: each MFMA's operand k-slot bijection is CHOSEN and used
// consistently for BOTH its A and B operands -> result invariant to the true HW
// bijection. QK uses sigma1(g,j)=g*8+j; PV uses sigma2(g,j)=(j>>2)*16+g*4+(j&3)
// (matches QK^T C/D register layout). C/D: col = lane&15, row = (lane>>4)*4 + reg.

typedef unsigned short u16;
typedef float f32x4 __attribute__((ext_vector_type(4)));
typedef __bf16 bf16x8 __attribute__((ext_vector_type(8)));
typedef unsigned short u16x4 __attribute__((ext_vector_type(4)));
typedef unsigned short u16x8 __attribute__((ext_vector_type(8)));

constexpr int Bn = 2, SEQ = 2048, NH = 16, HD = 64, HID = 1024;
constexpr size_t NX = (size_t)Bn * SEQ * HID;  // 4,194,304
constexpr size_t NW = (size_t)HID * HID;       // 1,048,576 = 1<<20

__device__ __forceinline__ u16 f2bf(float f) {
  unsigned u = __float_as_uint(f);
  u += 0x7fff + ((u >> 16) & 1);  // RNE
  return (u16)(u >> 16);
}

__device__ __forceinline__ f32x4 mfma16(bf16x8 a, bf16x8 b, f32x4 c) {
  return __builtin_amdgcn_mfma_f32_16x16x32_bf16(a, b, c, 0, 0, 0);
}

__device__ __forceinline__ void gload16(const u16* g, u16* l) {
  __builtin_amdgcn_global_load_lds(
      (const __attribute__((address_space(1))) unsigned int*)(const void*)g,
      (__attribute__((address_space(3))) unsigned int*)(void*)l, 16, 0, 0);
}

// One dispatch converting x, Wq, Wk, Wv, Wp to bf16.
__global__ void cvt_all(const float* __restrict__ x,
                        const float* __restrict__ Wq, const float* __restrict__ Wk,
                        const float* __restrict__ Wv, const float* __restrict__ Wp,
                        u16* __restrict__ xb, u16* __restrict__ wqb, u16* __restrict__ wkb,
                        u16* __restrict__ wvb, u16* __restrict__ wpb) {
  size_t i = ((size_t)blockIdx.x * blockDim.x + threadIdx.x) * 4;
  const float* s; u16* d; size_t off;
  if (i < NX) { s = x; d = xb; off = i; }
  else {
    size_t k = i - NX;
    int id = (int)(k >> 20);
    off = k & (NW - 1);
    s = (id == 0) ? Wq : (id == 1) ? Wk : (id == 2) ? Wv : Wp;
    d = (id == 0) ? wqb : (id == 1) ? wkb : (id == 2) ? wvb : wpb;
  }
  float4 v = *reinterpret_cast<const float4*>(s + off);
  u16x4 o = {f2bf(v.x), f2bf(v.y), f2bf(v.z), f2bf(v.w)};
  *reinterpret_cast<u16x4*>(d + off) = o;
}

// Fused QKV projection: grid (24 n-panels, 32 m-tiles); x-fastest dispatch ->
// weight panel x pinned to XCD x&7 (3 panels/XCD L2-resident).
// Q,K -> [b,h,s,d]; V -> [b,h,d,s] via LDS transpose epilogue.
__global__ __launch_bounds__(256) void qkv_gemm(
    const u16* __restrict__ A,
    const u16* __restrict__ W0, const u16* __restrict__ W1, const u16* __restrict__ W2,
    const float* __restrict__ b0, const float* __restrict__ b1, const float* __restrict__ b2,
    u16* __restrict__ out0, u16* __restrict__ out1, u16* __restrict__ out2)
{
  constexpr int K = HID;
  __shared__ u16 smem[16384];  // As[2]=smem[0..8191], Bs[2]=smem[8192..16383]; epilogue reuse 32KB
  const int tid = threadIdx.x;
  const int lane = tid & 63, w = tid >> 6;
  const int wr = w >> 1, wc = w & 1;
  const int l15 = lane & 15, g = lane >> 4;
  const int m0 = blockIdx.y * 128;
  const int n0g = blockIdx.x * 128;
  const int id = n0g >> 10;
  const int n0 = n0g & (HID - 1);
  const u16* Bm = (id == 0) ? W0 : (id == 1) ? W1 : W2;
  const float* bias = (id == 0) ? b0 : (id == 1) ? b1 : b2;

  auto stage = [&](int buf, int kt) {
#pragma unroll
    for (int i = 0; i < 2; i++) {
      int chunk = tid + 256 * i;
      int r = chunk >> 2, c = (chunk & 3) << 3;
      gload16(&A[(size_t)(m0 + r) * K + kt + c], &smem[buf * 4096 + chunk * 8]);
      gload16(&Bm[(size_t)(n0 + r) * K + kt + c], &smem[8192 + buf * 4096 + chunk * 8]);
    }
  };

  f32x4 acc[4][4] = {};
  stage(0, 0);

  for (int ki = 0; ki < 32; ki++) {
    const int buf = ki & 1;
    __syncthreads();  // vmcnt(0): stage(ki) landed (issued a full compute phase ago)
    if (ki + 1 < 32) stage(buf ^ 1, (ki + 1) * 32);
    const u16* As = &smem[buf * 4096];
    const u16* Bs = &smem[8192 + buf * 4096];
    bf16x8 af[4], bfr[4];
#pragma unroll
    for (int mi = 0; mi < 4; mi++)
      af[mi] = *reinterpret_cast<const bf16x8*>(&As[(wr * 64 + mi * 16 + l15) * 32 + g * 8]);
#pragma unroll
    for (int ni = 0; ni < 4; ni++)
      bfr[ni] = *reinterpret_cast<const bf16x8*>(&Bs[(wc * 64 + ni * 16 + l15) * 32 + g * 8]);
#pragma unroll
    for (int mi = 0; mi < 4; mi++)
#pragma unroll
      for (int ni = 0; ni < 4; ni++)
        acc[mi][ni] = mfma16(af[mi], bfr[ni], acc[mi][ni]);
  }

  float bv[4];
#pragma unroll
  for (int ni = 0; ni < 4; ni++) bv[ni] = bias[n0 + wc * 64 + ni * 16 + l15];

  if (id == 2) {
    // V^T: transpose 128(sq) x 128(d) tile through swizzled LDS, store along s.
    __syncthreads();  // K-loop LDS reads done everywhere; reuse smem
#pragma unroll
    for (int mi = 0; mi < 4; mi++)
#pragma unroll
      for (int ni = 0; ni < 4; ni++) {
        u16x4 pk;
#pragma unroll
        for (int r = 0; r < 4; r++) pk[r] = f2bf(acc[mi][ni][r] + bv[ni]);
        int d_loc = wc * 64 + ni * 16 + l15;
        int sq_base = wr * 64 + mi * 16 + g * 4;
        *reinterpret_cast<u16x4*>(
            &smem[d_loc * 128 + (sq_base ^ ((d_loc & 7) << 4))]) = pk;
      }
    __syncthreads();
    const int bb = m0 >> 11;
    const int sq0 = m0 & (SEQ - 1);
#pragma unroll
    for (int i = 0; i < 8; i++) {
      int chunk = tid + 256 * i;           // 0..2047
      int d_loc = chunk >> 4;              // 0..127
      int sqc = (chunk & 15) << 3;         // 0..120, step 8
      u16x8 val = *reinterpret_cast<const u16x8*>(
          &smem[d_loc * 128 + (sqc ^ ((d_loc & 7) << 4))]);
      int gn = n0 + d_loc;
      int hh = gn >> 6, dd = gn & 63;
      *reinterpret_cast<u16x8*>(
          &out2[((size_t)(bb * NH + hh) * HD + dd) * SEQ + sq0 + sqc]) = val;
    }
  } else {
    u16* out = (id == 0) ? out0 : out1;
#pragma unroll
    for (int mi = 0; mi < 4; mi++)
#pragma unroll
      for (int ni = 0; ni < 4; ni++)
#pragma unroll
        for (int r = 0; r < 4; r++) {
          int gm = m0 + wr * 64 + mi * 16 + g * 4 + r;
          int gn = n0 + wc * 64 + ni * 16 + l15;
          int bb = gm >> 11, sq = gm & (SEQ - 1);
          int hh = gn >> 6, d = gn & 63;
          out[((size_t)(bb * NH + hh) * SEQ + sq) * HD + d] = f2bf(acc[mi][ni][r] + bv[ni]);
        }
  }
}

// Output projection: out = Y @ Wp^T + bp, fp32. 64(M)x128(N) tiles, grid (8, 64):
// weight panel x pinned to XCD x (exactly one 256KB panel per XCD).
__global__ __launch_bounds__(256) void gemm_out(
    const u16* __restrict__ A, const u16* __restrict__ Bm,
    const float* __restrict__ bias, float* __restrict__ out)
{
  constexpr int K = HID, N = HID;
  __shared__ u16 As[2][64 * 32];
  __shared__ u16 Bs[2][128 * 32];
  const int tid = threadIdx.x;
  const int lane = tid & 63, w = tid >> 6;
  const int l15 = lane & 15, g = lane >> 4;
  const int m0 = blockIdx.y * 64, n0 = blockIdx.x * 128;

  auto stage = [&](int buf, int kt) {
    {
      int r = tid >> 2, c = (tid & 3) << 3;
      gload16(&A[(size_t)(m0 + r) * K + kt + c], &As[buf][tid * 8]);
    }
#pragma unroll
    for (int i = 0; i < 2; i++) {
      int chunk = tid + 256 * i;
      int r = chunk >> 2, c = (chunk & 3) << 3;
      gload16(&Bm[(size_t)(n0 + r) * K + kt + c], &Bs[buf][chunk * 8]);
    }
  };

  f32x4 acc[4][2] = {};
  stage(0, 0);

  for (int ki = 0; ki < 32; ki++) {
    const int buf = ki & 1;
    __syncthreads();
    if (ki + 1 < 32) stage(buf ^ 1, (ki + 1) * 32);
    bf16x8 af[4], bfr[2];
#pragma unroll
    for (int mi = 0; mi < 4; mi++)
      af[mi] = *reinterpret_cast<const bf16x8*>(&As[buf][(mi * 16 + l15) * 32 + g * 8]);
#pragma unroll
    for (int ni = 0; ni < 2; ni++)
      bfr[ni] = *reinterpret_cast<const bf16x8*>(&Bs[buf][(w * 32 + ni * 16 + l15) * 32 + g * 8]);
#pragma unroll
    for (int mi = 0; mi < 4; mi++)
#pragma unroll
      for (int ni = 0; ni < 2; ni++)
        acc[mi][ni] = mfma16(af[mi], bfr[ni], acc[mi][ni]);
  }

  float bv[2];
#pragma unroll
  for (int ni = 0; ni < 2; ni++) bv[ni] = bias[n0 + w * 32 + ni * 16 + l15];

#pragma unroll
  for (int mi = 0; mi < 4; mi++)
#pragma unroll
    for (int ni = 0; ni < 2; ni++)
#pragma unroll
      for (int r = 0; r < 4; r++) {
        int gm = m0 + mi * 16 + g * 4 + r;
        int gn = n0 + w * 32 + ni * 16 + l15;
        out[(size_t)gm * N + gn] = acc[mi][ni][r] + bv[ni];
      }
}

// Flash attention, causal. Grid 1024 (all co-resident, 4 blocks/CU).
// bid -> (xcd, bh, tile) with per-CU balanced tiles {24+s, 23-s, 8+s, 7-s}.
// Double-buffered K/V LDS (32KB), stage-after-barrier. Swapped QK^T; P in regs.
// Chain-minimized softmax: per-lane l partial, trigger-only max (no per-iter shfl).
__global__ __launch_bounds__(256, 4) void attn_kernel(
    const u16* __restrict__ Q, const u16* __restrict__ Kt,
    const u16* __restrict__ Vt, u16* __restrict__ Y)
{
  __shared__ u16 smK[2][4096];  // [buf][64 keys][64 d]   (swizzled slots)
  __shared__ u16 smV[2][4096];  // [buf][64 d][64 keys]   (swizzled slots)
  const int tid = threadIdx.x;
  const int lane = tid & 63, w = tid >> 6;
  const int l15 = lane & 15, g = lane >> 4;
  const int bid = blockIdx.x;          // 0..1023
  const int q = bid >> 8;              // round 0..3 (same CU across rounds)
  const int rr = bid & 255;
  const int xcd = rr & 7;
  const int cu = (rr >> 3) & 31;       // CU slot within XCD
  const int bh = xcd * 4 + (cu & 3);   // 4 bh pinned per XCD
  const int s = cu >> 2;               // 0..7
  int tile;
  if (q == 0) tile = 24 + s;
  else if (q == 1) tile = 23 - s;
  else if (q == 2) tile = 8 + s;
  else tile = 7 - s;
  const int b = bh >> 4, h = bh & 15;
  const int xs = l15 & 7;  // read-side XOR

  const int nt = tile + 1;
  const int q0 = tile * 64 + w * 16;
  const int qg = q0 + l15;

  const size_t bhs = (size_t)bh;
  const u16* Qp = Q + bhs * SEQ * HD;
  const u16* Kp = Kt + bhs * SEQ * HD;
  const u16* Vp = Vt + bhs * HD * SEQ;  // [d][s]

  int srow[2], sslot[2];
#pragma unroll
  for (int it = 0; it < 2; it++) {
    int idx = it * 256 + tid;
    srow[it] = idx >> 3;
    sslot[it] = (idx & 7) ^ (srow[it] & 7);  // pre-swizzled global source slot
  }
  auto stage = [&](int buf, int kt) {
#pragma unroll
    for (int it = 0; it < 2; it++) {
      int idx = it * 256 + tid;
      gload16(Kp + (size_t)(kt + srow[it]) * HD + sslot[it] * 8, &smK[buf][idx * 8]);
      gload16(Vp + (size_t)srow[it] * SEQ + kt + sslot[it] * 8, &smV[buf][idx * 8]);
    }
  };

  const float QSC = 0.125f * 1.44269504088896f;  // 1/sqrt(64) * log2(e)
  const float NEG = -__builtin_inff();

  // Q fragments (B operand, sigma1)
  bf16x8 tq0 = *reinterpret_cast<const bf16x8*>(Qp + (size_t)qg * HD + g * 8);
  bf16x8 tq1 = *reinterpret_cast<const bf16x8*>(Qp + (size_t)qg * HD + 32 + g * 8);
  stage(0, 0);
  bf16x8 qf[2];
#pragma unroll
  for (int jj = 0; jj < 8; jj++) {
    qf[0][jj] = (__bf16)((float)tq0[jj] * QSC);
    qf[1][jj] = (__bf16)((float)tq1[jj] * QSC);
  }

  float m_run = NEG;
  float l_lane = 0.0f;   // per-lane partial; cross-lane reduced AFTER the loop
  f32x4 o[4] = {};       // O^T[d][q]: d = db*16 + g*4 + r, q = l15

  // one iteration body; MASKED resolves to a constant after inlining
  auto iter_body = [&](int t, bool MASKED) __attribute__((always_inline)) {
    const int kt = t * 64;
    const int buf = t & 1;
    __syncthreads();  // stage(t) landed (issued a full iteration ago); buf^1 readers done
    if (t + 1 < nt) stage(buf ^ 1, kt + 64);
    const u16* K_ = smK[buf];
    const u16* V_ = smV[buf];

    // ---- QK^T: S^T (log2 domain), key = kt + sub*16 + g*4 + r, q = l15
    f32x4 sa[4];
#pragma unroll
    for (int sub = 0; sub < 4; sub++) {
      int row = sub * 16 + l15;
      bf16x8 k0 = *reinterpret_cast<const bf16x8*>(&K_[row * 64 + ((0 + g) ^ xs) * 8]);
      bf16x8 k1 = *reinterpret_cast<const bf16x8*>(&K_[row * 64 + ((4 + g) ^ xs) * 8]);
      f32x4 a = {0.f, 0.f, 0.f, 0.f};
      a = mfma16(k0, qf[0], a);
      a = mfma16(k1, qf[1], a);
      sa[sub] = a;
    }

    float p[16];
    if (MASKED) {
#pragma unroll
      for (int sub = 0; sub < 4; sub++)
#pragma unroll
        for (int r = 0; r < 4; r++) {
          int key = kt + sub * 16 + g * 4 + r;
          p[sub * 4 + r] = (key <= qg) ? sa[sub][r] : NEG;
        }
    } else {
#pragma unroll
      for (int sub = 0; sub < 4; sub++)
#pragma unroll
        for (int r = 0; r < 4; r++) p[sub * 4 + r] = sa[sub][r];
    }

    // ---- per-LANE max tree (no cross-lane shfl in the common path)
    float a0 = fmaxf(fmaxf(p[0], p[1]), p[2]);
    float a1 = fmaxf(fmaxf(p[3], p[4]), p[5]);
    float a2 = fmaxf(fmaxf(p[6], p[7]), p[8]);
    float a3 = fmaxf(fmaxf(p[9], p[10]), p[11]);
    float a4 = fmaxf(fmaxf(p[12], p[13]), p[14]);
    float b0 = fmaxf(fmaxf(a0, a1), p[15]);
    float tloc = fmaxf(fmaxf(b0, a2), fmaxf(a3, a4));

    // trigger-only rescale: rare (first tile, then ~never for N(0,1) scores)
    if (__any(tloc > m_run + 11.0f)) {
      float tmax = tloc;
      tmax = fmaxf(tmax, __shfl_xor(tmax, 16));
      tmax = fmaxf(tmax, __shfl_xor(tmax, 32));
      float mnew = fmaxf(m_run, tmax);
      float fs = __builtin_amdgcn_exp2f(m_run - mnew);  // 0 when m_run=-inf
      l_lane *= fs;
#pragma unroll
      for (int db = 0; db < 4; db++) o[db] *= fs;
      m_run = mnew;
    }

    // ---- P = 2^(p - m_run); per-lane partial sum; pack via compiler cvt_pk
    float pe[16];
    float s4[4] = {0.f, 0.f, 0.f, 0.f};
#pragma unroll
    for (int i = 0; i < 16; i++) {
      pe[i] = __builtin_amdgcn_exp2f(p[i] - m_run);
      s4[i & 3] += pe[i];
    }

    // ---- O^T += V^T * P^T; sigma2(g,j) = (j>>2)*16 + g*4 + (j&3)
#pragma unroll
    for (int half = 0; half < 2; half++) {
      bf16x8 pb;
#pragma unroll
      for (int jj = 0; jj < 8; jj++) pb[jj] = (__bf16)pe[8 * half + jj];
      const int s0 = ((4 * half + (g >> 1)) ^ xs) * 8 + 4 * (g & 1);
      const int s1 = ((4 * half + 2 + (g >> 1)) ^ xs) * 8 + 4 * (g & 1);
#pragma unroll
      for (int db = 0; db < 4; db++) {
        int vbase = (db * 16 + l15) * 64;
        u16x4 v0 = *reinterpret_cast<const u16x4*>(&V_[vbase + s0]);
        u16x4 v1 = *reinterpret_cast<const u16x4*>(&V_[vbase + s1]);
        u16x8 vau;
#pragma unroll
        for (int jj = 0; jj < 4; jj++) { vau[jj] = v0[jj]; vau[jj + 4] = v1[jj]; }
        bf16x8 va = __builtin_bit_cast(bf16x8, vau);
        o[db] = mfma16(va, pb, o[db]);
      }
    }

    l_lane += (s4[0] + s4[1]) + (s4[2] + s4[3]);
  };

  for (int t = 0; t < nt - 1; t++) iter_body(t, false);
  iter_body(nt - 1, true);  // peeled: causal mask only here

  // ---- final cross-lane l reduce (once per tile, not per iteration)
  float l_tot = l_lane;
  l_tot += __shfl_xor(l_tot, 16);
  l_tot += __shfl_xor(l_tot, 32);
  float rl = 1.0f / l_tot;
#pragma unroll
  for (int db = 0; db < 4; db++) {
    u16x4 yo;
#pragma unroll
    for (int r = 0; r < 4; r++) yo[r] = f2bf(o[db][r] * rl);
    *reinterpret_cast<u16x4*>(
        Y + ((size_t)(b * SEQ) + qg) * HID + h * HD + db * 16 + g * 4) = yo;
  }
}

extern "C" void kernel_launch(void* const* d_in, const int* in_sizes, int n_in,
                              void* d_out, int out_size, void* d_ws, size_t ws_size,
                              hipStream_t stream) {
  const float* x  = (const float*)d_in[0];
  const float* Wq = (const float*)d_in[1];
  const float* bq = (const float*)d_in[2];
  const float* Wk = (const float*)d_in[3];
  const float* bk = (const float*)d_in[4];
  const float* Wv = (const float*)d_in[5];
  const float* bv = (const float*)d_in[6];
  const float* Wp = (const float*)d_in[7];
  const float* bp = (const float*)d_in[8];

  u16* ws = (u16*)d_ws;
  u16* xb  = ws; ws += NX;
  u16* wqb = ws; ws += NW;
  u16* wkb = ws; ws += NW;
  u16* wvb = ws; ws += NW;
  u16* wpb = ws; ws += NW;
  u16* Qb  = ws; ws += NX;
  u16* Kb  = ws; ws += NX;
  u16* Vtb = ws; ws += NX;
  u16* Yb  = ws; ws += NX;   // total ~48 MB of d_ws

  const unsigned cvtBlocks = (unsigned)((NX + 4 * NW) / 4 / 256);  // 8192
  cvt_all<<<cvtBlocks, 256, 0, stream>>>(x, Wq, Wk, Wv, Wp, xb, wqb, wkb, wvb, wpb);

  qkv_gemm<<<dim3(24, 32), 256, 0, stream>>>(xb, wqb, wkb, wvb, bq, bk, bv, Qb, Kb, Vtb);

  attn_kernel<<<dim3(1024), 256, 0, stream>>>(Qb, Kb, Vtb, Yb);

  gemm_out<<<dim3(8, 64), 256, 0, stream>>>(Yb, wpb, bp, (float*)d_out);
}